// Round 1
// baseline (2117.547 us; speedup 1.0000x reference)
//
#include <hip/hip_runtime.h>
#include <math.h>

#define N_NODES 100000
#define N_EDGES 1600000
#define D 128

// ---------------- CSR build ----------------

__global__ void k_hist(const int* __restrict__ dst, int* __restrict__ deg) {
    int e = blockIdx.x * 256 + threadIdx.x;
    if (e < N_EDGES) atomicAdd(&deg[dst[e]], 1);
}

__global__ void k_scan1(const int* __restrict__ deg, int* __restrict__ offs,
                        int* __restrict__ bsums) {
    __shared__ int tmp[256];
    int tid = threadIdx.x;
    int i = blockIdx.x * 256 + tid;
    int v = (i < N_NODES) ? deg[i] : 0;
    tmp[tid] = v;
    __syncthreads();
    for (int off = 1; off < 256; off <<= 1) {
        int t = (tid >= off) ? tmp[tid - off] : 0;
        __syncthreads();
        if (tid >= off) tmp[tid] += t;
        __syncthreads();
    }
    if (i < N_NODES) offs[i] = tmp[tid] - v;   // exclusive, pre-block-offset
    if (tid == 255) bsums[blockIdx.x] = tmp[255];
}

__global__ void k_scan2(int* __restrict__ bsums, int nb) {
    __shared__ int tmp[512];
    int tid = threadIdx.x;
    int v = (tid < nb) ? bsums[tid] : 0;
    tmp[tid] = v;
    __syncthreads();
    for (int off = 1; off < 512; off <<= 1) {
        int t = (tid >= off) ? tmp[tid - off] : 0;
        __syncthreads();
        if (tid >= off) tmp[tid] += t;
        __syncthreads();
    }
    if (tid < nb) bsums[tid] = tmp[tid] - v;   // exclusive scan of block sums
}

__global__ void k_scan3(const int* __restrict__ deg, int* __restrict__ offs,
                        const int* __restrict__ bsums, int* __restrict__ cursor,
                        float* __restrict__ inv_deg) {
    int i = blockIdx.x * 256 + threadIdx.x;
    if (i < N_NODES) {
        int o = offs[i] + bsums[blockIdx.x];
        offs[i] = o;
        cursor[i] = o;
        int d = deg[i];
        inv_deg[i] = 1.0f / (float)(d > 1 ? d : 1);
        if (i == 0) offs[N_NODES] = N_EDGES;
    }
}

__global__ void k_fill(const int* __restrict__ src, const int* __restrict__ dst,
                       int* __restrict__ cursor, int* __restrict__ csr_src) {
    int e = blockIdx.x * 256 + threadIdx.x;
    if (e < N_EDGES) {
        int p = atomicAdd(&cursor[dst[e]], 1);
        csr_src[p] = src[e];
    }
}

// ---------------- mean aggregation (CSR gather) ----------------
// one wave (64 lanes) per node; lane holds 2 consecutive floats of the row
__global__ void k_agg(const float* __restrict__ h, const int* __restrict__ offs,
                      const int* __restrict__ csr_src, const float* __restrict__ inv_deg,
                      float* __restrict__ agg) {
    int node = blockIdx.x * 4 + (threadIdx.x >> 6);
    int lane = threadIdx.x & 63;
    int beg = offs[node], end = offs[node + 1];
    float ax = 0.f, ay = 0.f;
    for (int e = beg; e < end; ++e) {
        int s = csr_src[e];
        float2 v = ((const float2*)(h + (size_t)s * D))[lane];
        ax += v.x;
        ay += v.y;
    }
    float id = inv_deg[node];
    float2 o;
    o.x = ax * id;
    o.y = ay * id;
    ((float2*)(agg + (size_t)node * D))[lane] = o;
}

// ---------------- fused layer: y = LN(relu(agg@Wl^T + b + h@Wr^T))*g + beta + skip --------
// block = 256 threads, tile = 32 nodes x 128 outputs, 4x4 register tile / thread.
template <bool L0>
__global__ __launch_bounds__(256) void k_layer(
    const float* __restrict__ agg, const float* __restrict__ hin,
    const float* __restrict__ Wl, const float* __restrict__ lb,
    const float* __restrict__ Wr,
    const float* __restrict__ projW, const float* __restrict__ projB,
    const float* __restrict__ g, const float* __restrict__ beta,
    float* __restrict__ hout) {
    __shared__ float sA[2][32][132];   // [0]=agg tile, [1]=hin tile (pad 132 kills bank conflicts)
    __shared__ float s_mu[32], s_rs[32];

    int tid = threadIdx.x;
    int base = blockIdx.x * 32;

    // stage 32x128 of agg and hin
    for (int idx = tid; idx < 32 * 32; idx += 256) {
        int row = idx >> 5;
        int c4 = (idx & 31) << 2;
        float4 va = *(const float4*)(agg + (size_t)(base + row) * D + c4);
        float4 vh = *(const float4*)(hin + (size_t)(base + row) * D + c4);
        *(float4*)&sA[0][row][c4] = va;
        *(float4*)&sA[1][row][c4] = vh;
    }
    __syncthreads();

    int tx = tid & 31, mg = tid >> 5;
    int n0 = tx * 4, m0 = mg * 4;

    float acc[4][4] = {};
    float accR[4][4] = {};

    // segment 0: agg @ Wl^T ; segment 1: hin @ Wr^T
    for (int seg = 0; seg < 2; ++seg) {
        const float* W = seg ? Wr : Wl;
        const float(*A)[132] = sA[seg];
#pragma unroll 4
        for (int k = 0; k < D; k += 4) {
            float4 av[4], wv[4];
#pragma unroll
            for (int i = 0; i < 4; ++i) av[i] = *(const float4*)&A[m0 + i][k];
#pragma unroll
            for (int j = 0; j < 4; ++j) wv[j] = *(const float4*)(W + (n0 + j) * D + k);
#pragma unroll
            for (int i = 0; i < 4; ++i)
#pragma unroll
                for (int j = 0; j < 4; ++j)
                    acc[i][j] += av[i].x * wv[j].x + av[i].y * wv[j].y +
                                 av[i].z * wv[j].z + av[i].w * wv[j].w;
        }
    }
    if (L0) {
        // residual = x @ projW^T + projB  (hin == x for layer 0)
        const float(*A)[132] = sA[1];
#pragma unroll 4
        for (int k = 0; k < D; k += 4) {
            float4 av[4], wv[4];
#pragma unroll
            for (int i = 0; i < 4; ++i) av[i] = *(const float4*)&A[m0 + i][k];
#pragma unroll
            for (int j = 0; j < 4; ++j) wv[j] = *(const float4*)(projW + (n0 + j) * D + k);
#pragma unroll
            for (int i = 0; i < 4; ++i)
#pragma unroll
                for (int j = 0; j < 4; ++j)
                    accR[i][j] += av[i].x * wv[j].x + av[i].y * wv[j].y +
                                  av[i].z * wv[j].z + av[i].w * wv[j].w;
        }
    }

    // bias + relu, stash for LN stats
    float yv[4][4];
#pragma unroll
    for (int j = 0; j < 4; ++j) {
        float bj = lb[n0 + j];
#pragma unroll
        for (int i = 0; i < 4; ++i) {
            float y = acc[i][j] + bj;
            y = fmaxf(y, 0.f);
            yv[i][j] = y;
        }
    }
    __syncthreads();   // done reading sA[0] as agg tile
#pragma unroll
    for (int i = 0; i < 4; ++i) {
        *(float4*)&sA[0][m0 + i][n0] = *(float4*)&yv[i][0];
    }
    __syncthreads();

    if (tid < 32) {
        float s = 0.f, ss = 0.f;
#pragma unroll 8
        for (int c = 0; c < D; ++c) {
            float v = sA[0][tid][c];
            s += v;
            ss += v * v;
        }
        float mu = s * (1.0f / 128.0f);
        float var = ss * (1.0f / 128.0f) - mu * mu;
        s_mu[tid] = mu;
        s_rs[tid] = rsqrtf(var + 1e-5f);
    }
    __syncthreads();

    float gv[4], bv[4];
#pragma unroll
    for (int j = 0; j < 4; ++j) {
        gv[j] = g[n0 + j];
        bv[j] = beta[n0 + j];
    }
#pragma unroll
    for (int i = 0; i < 4; ++i) {
        float mu = s_mu[m0 + i], rs = s_rs[m0 + i];
        float4 o;
        float ov[4];
#pragma unroll
        for (int j = 0; j < 4; ++j) {
            float r = L0 ? (accR[i][j] + projB[n0 + j]) : sA[1][m0 + i][n0 + j];
            ov[j] = (yv[i][j] - mu) * rs * gv[j] + bv[j] + r;
        }
        o.x = ov[0]; o.y = ov[1]; o.z = ov[2]; o.w = ov[3];
        *(float4*)(hout + (size_t)(base + m0 + i) * D + n0) = o;
    }
}

// ---------------- head: out = a*rr + (1-a)*(h @ head_w + head_b) ----------------
__global__ void k_head(const float* __restrict__ h, const float* __restrict__ hw,
                       const float* __restrict__ hb, const float* __restrict__ rr,
                       const float* __restrict__ alpha, float* __restrict__ out) {
    int node = blockIdx.x * 4 + (threadIdx.x >> 6);
    int lane = threadIdx.x & 63;
    float2 w = ((const float2*)hw)[lane];
    float2 v = ((const float2*)(h + (size_t)node * D))[lane];
    float s = v.x * w.x + v.y * w.y;
#pragma unroll
    for (int off = 32; off > 0; off >>= 1) s += __shfl_down(s, off, 64);
    if (lane == 0) {
        float a = 1.0f / (1.0f + expf(-alpha[0]));
        out[node] = a * rr[node] + (1.0f - a) * (s + hb[0]);
    }
}

// ---------------- launch ----------------
extern "C" void kernel_launch(void* const* d_in, const int* in_sizes, int n_in,
                              void* d_out, int out_size, void* d_ws, size_t ws_size,
                              hipStream_t stream) {
    const float* x     = (const float*)d_in[0];
    const int*   ei    = (const int*)d_in[1];
    const float* rr    = (const float*)d_in[2];
    const float* projW = (const float*)d_in[3];
    const float* projB = (const float*)d_in[4];
    const float* WlAll = (const float*)d_in[5];
    const float* lbAll = (const float*)d_in[6];
    const float* WrAll = (const float*)d_in[7];
    const float* gAll  = (const float*)d_in[8];
    const float* btAll = (const float*)d_in[9];
    const float* hw    = (const float*)d_in[10];
    const float* hb    = (const float*)d_in[11];
    const float* alpha = (const float*)d_in[12];
    float* out = (float*)d_out;

    char* p = (char*)d_ws;
    float* agg = (float*)p; p += (size_t)N_NODES * D * 4;
    float* h0  = (float*)p; p += (size_t)N_NODES * D * 4;
    float* h1  = (float*)p; p += (size_t)N_NODES * D * 4;
    int* deg     = (int*)p; p += (size_t)N_NODES * 4;
    float* invd  = (float*)p; p += (size_t)N_NODES * 4;
    int* offs    = (int*)p; p += (size_t)(N_NODES + 2) * 4;
    int* cursor  = (int*)p; p += (size_t)N_NODES * 4;
    int* csr_src = (int*)p; p += (size_t)N_EDGES * 4;
    int* bsums   = (int*)p; p += 512 * 4;

    const int* src = ei;
    const int* dst = ei + N_EDGES;

    hipMemsetAsync(deg, 0, (size_t)N_NODES * 4, stream);
    k_hist<<<(N_EDGES + 255) / 256, 256, 0, stream>>>(dst, deg);
    int nb = (N_NODES + 255) / 256;   // 391
    k_scan1<<<nb, 256, 0, stream>>>(deg, offs, bsums);
    k_scan2<<<1, 512, 0, stream>>>(bsums, nb);
    k_scan3<<<nb, 256, 0, stream>>>(deg, offs, bsums, cursor, invd);
    k_fill<<<(N_EDGES + 255) / 256, 256, 0, stream>>>(src, dst, cursor, csr_src);

    // layer 0 (h = x)
    k_agg<<<N_NODES / 4, 256, 0, stream>>>(x, offs, csr_src, invd, agg);
    k_layer<true><<<N_NODES / 32, 256, 0, stream>>>(agg, x, WlAll, lbAll, WrAll,
                                                    projW, projB, gAll, btAll, h0);
    // layer 1
    k_agg<<<N_NODES / 4, 256, 0, stream>>>(h0, offs, csr_src, invd, agg);
    k_layer<false><<<N_NODES / 32, 256, 0, stream>>>(agg, h0, WlAll + D * D, lbAll + D,
                                                     WrAll + D * D, nullptr, nullptr,
                                                     gAll + D, btAll + D, h1);
    // layer 2
    k_agg<<<N_NODES / 4, 256, 0, stream>>>(h1, offs, csr_src, invd, agg);
    k_layer<false><<<N_NODES / 32, 256, 0, stream>>>(agg, h1, WlAll + 2 * D * D, lbAll + 2 * D,
                                                     WrAll + 2 * D * D, nullptr, nullptr,
                                                     gAll + 2 * D, btAll + 2 * D, h0);

    k_head<<<N_NODES / 4, 256, 0, stream>>>(h0, hw, hb, rr, alpha, out);
}

// Round 3
// 1198.200 us; speedup vs baseline: 1.7673x; 1.7673x over previous
//
#include <hip/hip_runtime.h>
#include <math.h>

#define N_NODES 100000
#define N_EDGES 1600000
#define D 128

typedef __attribute__((ext_vector_type(8))) short short8;
typedef __attribute__((ext_vector_type(4))) float floatx4;

__device__ __forceinline__ float bf2f(unsigned short u) {
    union { unsigned int i; float f; } v;
    v.i = ((unsigned int)u) << 16;
    return v.f;
}
__device__ __forceinline__ unsigned short f2bf(float f) {
    union { float f; unsigned int i; } v;
    v.f = f;
    unsigned int u = v.i;
    u += 0x7fffu + ((u >> 16) & 1u);
    return (unsigned short)(u >> 16);
}

// split 8 consecutive fp32 into hi/lo bf16 fragments
__device__ __forceinline__ void split8(const float* __restrict__ p, short8& hi, short8& lo) {
    float4 v0 = *(const float4*)p;
    float4 v1 = *(const float4*)(p + 4);
    float f[8] = {v0.x, v0.y, v0.z, v0.w, v1.x, v1.y, v1.z, v1.w};
#pragma unroll
    for (int i = 0; i < 8; ++i) {
        unsigned short h = f2bf(f[i]);
        hi[i] = (short)h;
        lo[i] = (short)f2bf(f[i] - bf2f(h));
    }
}

// ---------------- weight split fp32 -> (hi,lo) bf16 ----------------
__global__ void k_cvt_split(const float* __restrict__ s, unsigned short* __restrict__ hi,
                            unsigned short* __restrict__ lo, int n4) {
    int i = blockIdx.x * 256 + threadIdx.x;
    if (i < n4) {
        float4 v = ((const float4*)s)[i];
        float f[4] = {v.x, v.y, v.z, v.w};
        ushort4 h, l;
        unsigned short* hp = (unsigned short*)&h;
        unsigned short* lp = (unsigned short*)&l;
#pragma unroll
        for (int c = 0; c < 4; ++c) {
            unsigned short hh = f2bf(f[c]);
            hp[c] = hh;
            lp[c] = f2bf(f[c] - bf2f(hh));
        }
        ((ushort4*)hi)[i] = h;
        ((ushort4*)lo)[i] = l;
    }
}

// ---------------- CSR build ----------------
__global__ void k_hist(const int* __restrict__ dst, int* __restrict__ deg) {
    int e = blockIdx.x * 256 + threadIdx.x;
    if (e < N_EDGES) atomicAdd(&deg[dst[e]], 1);
}

__global__ void k_scan1(const int* __restrict__ deg, int* __restrict__ offs,
                        int* __restrict__ bsums) {
    __shared__ int tmp[256];
    int tid = threadIdx.x;
    int i = blockIdx.x * 256 + tid;
    int v = (i < N_NODES) ? deg[i] : 0;
    tmp[tid] = v;
    __syncthreads();
    for (int off = 1; off < 256; off <<= 1) {
        int t = (tid >= off) ? tmp[tid - off] : 0;
        __syncthreads();
        if (tid >= off) tmp[tid] += t;
        __syncthreads();
    }
    if (i < N_NODES) offs[i] = tmp[tid] - v;
    if (tid == 255) bsums[blockIdx.x] = tmp[255];
}

__global__ void k_scan2(int* __restrict__ bsums, int nb) {
    __shared__ int tmp[512];
    int tid = threadIdx.x;
    int v = (tid < nb) ? bsums[tid] : 0;
    tmp[tid] = v;
    __syncthreads();
    for (int off = 1; off < 512; off <<= 1) {
        int t = (tid >= off) ? tmp[tid - off] : 0;
        __syncthreads();
        if (tid >= off) tmp[tid] += t;
        __syncthreads();
    }
    if (tid < nb) bsums[tid] = tmp[tid] - v;
}

__global__ void k_scan3(const int* __restrict__ deg, int* __restrict__ offs,
                        const int* __restrict__ bsums, int* __restrict__ cursor,
                        float* __restrict__ inv_deg) {
    int i = blockIdx.x * 256 + threadIdx.x;
    if (i < N_NODES) {
        int o = offs[i] + bsums[blockIdx.x];
        offs[i] = o;
        cursor[i] = o;
        int d = deg[i];
        inv_deg[i] = 1.0f / (float)(d > 1 ? d : 1);
        if (i == 0) offs[N_NODES] = N_EDGES;
    }
}

__global__ void k_fill(const int* __restrict__ src, const int* __restrict__ dst,
                       int* __restrict__ cursor, int* __restrict__ csr_src) {
    int e = blockIdx.x * 256 + threadIdx.x;
    if (e < N_EDGES) {
        int p = atomicAdd(&cursor[dst[e]], 1);
        csr_src[p] = src[e];
    }
}

// ---------------- mean aggregation (CSR gather, fp32) ----------------
__global__ void k_agg(const float* __restrict__ h, const int* __restrict__ offs,
                      const int* __restrict__ csr_src, const float* __restrict__ inv_deg,
                      float* __restrict__ agg) {
    int node = blockIdx.x * 4 + (threadIdx.x >> 6);
    int lane = threadIdx.x & 63;
    int beg = offs[node], end = offs[node + 1];
    float ax = 0.f, ay = 0.f;
    for (int e = beg; e < end; ++e) {
        int s = csr_src[e];
        float2 v = ((const float2*)(h + (size_t)s * D))[lane];
        ax += v.x;
        ay += v.y;
    }
    float id = inv_deg[node];
    float2 o;
    o.x = ax * id;
    o.y = ay * id;
    ((float2*)(agg + (size_t)node * D))[lane] = o;
}

// ---------------- split-bf16 GEMM segment: acc += A @ B^T (fp32-accurate) ------
// A rows fp32 (split on the fly), B pre-split hi/lo bf16.
__device__ __forceinline__ void gemm_seg(
    const float* __restrict__ arow0, const float* __restrict__ arow1,
    const unsigned short* __restrict__ b0h_, const unsigned short* __restrict__ b0l_,
    const unsigned short* __restrict__ b1h_, const unsigned short* __restrict__ b1l_,
    int koff, floatx4 acc[2][2]) {
#pragma unroll
    for (int ks = 0; ks < 4; ++ks) {
        int k0 = ks * 32 + koff;
        short8 a0h, a0l, a1h, a1l;
        split8(arow0 + k0, a0h, a0l);
        split8(arow1 + k0, a1h, a1l);
        short8 b0h = *(const short8*)(b0h_ + k0);
        short8 b0l = *(const short8*)(b0l_ + k0);
        short8 b1h = *(const short8*)(b1h_ + k0);
        short8 b1l = *(const short8*)(b1l_ + k0);
        acc[0][0] = __builtin_amdgcn_mfma_f32_16x16x32_bf16(a0h, b0h, acc[0][0], 0, 0, 0);
        acc[0][0] = __builtin_amdgcn_mfma_f32_16x16x32_bf16(a0h, b0l, acc[0][0], 0, 0, 0);
        acc[0][0] = __builtin_amdgcn_mfma_f32_16x16x32_bf16(a0l, b0h, acc[0][0], 0, 0, 0);
        acc[0][1] = __builtin_amdgcn_mfma_f32_16x16x32_bf16(a0h, b1h, acc[0][1], 0, 0, 0);
        acc[0][1] = __builtin_amdgcn_mfma_f32_16x16x32_bf16(a0h, b1l, acc[0][1], 0, 0, 0);
        acc[0][1] = __builtin_amdgcn_mfma_f32_16x16x32_bf16(a0l, b1h, acc[0][1], 0, 0, 0);
        acc[1][0] = __builtin_amdgcn_mfma_f32_16x16x32_bf16(a1h, b0h, acc[1][0], 0, 0, 0);
        acc[1][0] = __builtin_amdgcn_mfma_f32_16x16x32_bf16(a1h, b0l, acc[1][0], 0, 0, 0);
        acc[1][0] = __builtin_amdgcn_mfma_f32_16x16x32_bf16(a1l, b0h, acc[1][0], 0, 0, 0);
        acc[1][1] = __builtin_amdgcn_mfma_f32_16x16x32_bf16(a1h, b1h, acc[1][1], 0, 0, 0);
        acc[1][1] = __builtin_amdgcn_mfma_f32_16x16x32_bf16(a1h, b1l, acc[1][1], 0, 0, 0);
        acc[1][1] = __builtin_amdgcn_mfma_f32_16x16x32_bf16(a1l, b1h, acc[1][1], 0, 0, 0);
    }
}

// ---------------- residual projection: res = x @ projW^T + projB (fp32 out) ------
__global__ __launch_bounds__(256) void k_linear(
    const float* __restrict__ xf, const unsigned short* __restrict__ Whi,
    const unsigned short* __restrict__ Wlo, const float* __restrict__ bias,
    float* __restrict__ outf) {
    int tid = threadIdx.x;
    int w = tid >> 6, lane = tid & 63;
    int quad = lane >> 4, l16 = lane & 15;
    int base = blockIdx.x * 32;

    floatx4 z = {0.f, 0.f, 0.f, 0.f};
    floatx4 acc[2][2] = {{z, z}, {z, z}};

    const float* arow0 = xf + (size_t)(base + l16) * D;
    const float* arow1 = arow0 + 16 * D;
    int n_ = w * 32 + l16;
    int koff = quad * 8;

    gemm_seg(arow0, arow1, Whi + n_ * D, Wlo + n_ * D,
             Whi + (n_ + 16) * D, Wlo + (n_ + 16) * D, koff, acc);

    float bj0 = bias[n_], bj1 = bias[n_ + 16];
    int col = w * 32 + l16;
#pragma unroll
    for (int mt = 0; mt < 2; ++mt) {
        int rbase = mt * 16 + quad * 4;
#pragma unroll
        for (int r = 0; r < 4; ++r) {
            size_t row = (size_t)(base + rbase + r) * D;
            outf[row + col] = acc[mt][0][r] + bj0;
            outf[row + col + 16] = acc[mt][1][r] + bj1;
        }
    }
}

// ---------------- fused SAGE layer (split-bf16 MFMA, fp32 storage) ----------------
__global__ __launch_bounds__(256) void k_layer(
    const float* __restrict__ aggf, const float* __restrict__ hf_in,
    const float* __restrict__ skipf,
    const unsigned short* __restrict__ Wlh, const unsigned short* __restrict__ Wll,
    const unsigned short* __restrict__ Wrh, const unsigned short* __restrict__ Wrl,
    const float* __restrict__ lb, const float* __restrict__ g,
    const float* __restrict__ beta, float* __restrict__ hf_out) {
    __shared__ float sY[32][132];
    __shared__ float s_mu[32], s_rs[32];

    int tid = threadIdx.x;
    int w = tid >> 6, lane = tid & 63;
    int quad = lane >> 4, l16 = lane & 15;
    int base = blockIdx.x * 32;

    floatx4 z = {0.f, 0.f, 0.f, 0.f};
    floatx4 acc[2][2] = {{z, z}, {z, z}};

    const float* arow0 = aggf + (size_t)(base + l16) * D;
    const float* arow1 = arow0 + 16 * D;
    const float* hrow0 = hf_in + (size_t)(base + l16) * D;
    const float* hrow1 = hrow0 + 16 * D;
    int n_ = w * 32 + l16;
    int koff = quad * 8;

    gemm_seg(arow0, arow1, Wlh + n_ * D, Wll + n_ * D,
             Wlh + (n_ + 16) * D, Wll + (n_ + 16) * D, koff, acc);
    gemm_seg(hrow0, hrow1, Wrh + n_ * D, Wrl + n_ * D,
             Wrh + (n_ + 16) * D, Wrl + (n_ + 16) * D, koff, acc);

    // bias + relu into LDS
    float bj0 = lb[n_], bj1 = lb[n_ + 16];
    int col = w * 32 + l16;
#pragma unroll
    for (int mt = 0; mt < 2; ++mt) {
        int rbase = mt * 16 + quad * 4;
#pragma unroll
        for (int r = 0; r < 4; ++r) {
            sY[rbase + r][col] = fmaxf(acc[mt][0][r] + bj0, 0.f);
            sY[rbase + r][col + 16] = fmaxf(acc[mt][1][r] + bj1, 0.f);
        }
    }
    __syncthreads();

    // LN stats: thread t -> row=t>>3, 16-col segment s=t&7
    int row = tid >> 3, s = tid & 7;
    const float* yrow = &sY[row][s * 16];
    float sum = 0.f, ss = 0.f;
#pragma unroll
    for (int c = 0; c < 16; c += 4) {
        float4 v = *(const float4*)(yrow + c);
        sum += v.x + v.y + v.z + v.w;
        ss += v.x * v.x + v.y * v.y + v.z * v.z + v.w * v.w;
    }
#pragma unroll
    for (int m = 1; m < 8; m <<= 1) {
        sum += __shfl_xor(sum, m, 64);
        ss += __shfl_xor(ss, m, 64);
    }
    if (s == 0) {
        float mu = sum * (1.0f / 128.0f);
        float var = ss * (1.0f / 128.0f) - mu * mu;
        s_mu[row] = mu;
        s_rs[row] = rsqrtf(var + 1e-5f);
    }
    __syncthreads();

    // epilogue: LN scale/shift + skip, fp32 write
    float mu = s_mu[row], rs = s_rs[row];
    const float* skiprow = skipf + (size_t)(base + row) * D + s * 16;
    float* orow = hf_out + (size_t)(base + row) * D + s * 16;
#pragma unroll
    for (int c = 0; c < 16; c += 4) {
        float4 y = *(const float4*)(yrow + c);
        float4 gg = *(const float4*)(g + s * 16 + c);
        float4 bb = *(const float4*)(beta + s * 16 + c);
        float4 sk = *(const float4*)(skiprow + c);
        float4 o;
        o.x = (y.x - mu) * rs * gg.x + bb.x + sk.x;
        o.y = (y.y - mu) * rs * gg.y + bb.y + sk.y;
        o.z = (y.z - mu) * rs * gg.z + bb.z + sk.z;
        o.w = (y.w - mu) * rs * gg.w + bb.w + sk.w;
        *(float4*)(orow + c) = o;
    }
}

// ---------------- head ----------------
__global__ void k_head(const float* __restrict__ h, const float* __restrict__ hw,
                       const float* __restrict__ hb_bias, const float* __restrict__ rr,
                       const float* __restrict__ alpha, float* __restrict__ out) {
    int node = blockIdx.x * 4 + (threadIdx.x >> 6);
    int lane = threadIdx.x & 63;
    float2 w = ((const float2*)hw)[lane];
    float2 v = ((const float2*)(h + (size_t)node * D))[lane];
    float s = v.x * w.x + v.y * w.y;
#pragma unroll
    for (int off = 32; off > 0; off >>= 1) s += __shfl_down(s, off, 64);
    if (lane == 0) {
        float a = 1.0f / (1.0f + expf(-alpha[0]));
        out[node] = a * rr[node] + (1.0f - a) * (s + hb_bias[0]);
    }
}

// ---------------- launch ----------------
extern "C" void kernel_launch(void* const* d_in, const int* in_sizes, int n_in,
                              void* d_out, int out_size, void* d_ws, size_t ws_size,
                              hipStream_t stream) {
    const float* x     = (const float*)d_in[0];
    const int*   ei    = (const int*)d_in[1];
    const float* rr    = (const float*)d_in[2];
    const float* projW = (const float*)d_in[3];
    const float* projB = (const float*)d_in[4];
    const float* WlAll = (const float*)d_in[5];
    const float* lbAll = (const float*)d_in[6];
    const float* WrAll = (const float*)d_in[7];
    const float* gAll  = (const float*)d_in[8];
    const float* btAll = (const float*)d_in[9];
    const float* hw    = (const float*)d_in[10];
    const float* hbias = (const float*)d_in[11];
    const float* alpha = (const float*)d_in[12];
    float* out = (float*)d_out;

    char* p = (char*)d_ws;
    float* agg = (float*)p; p += (size_t)N_NODES * D * 4;
    float* h0  = (float*)p; p += (size_t)N_NODES * D * 4;
    float* h1  = (float*)p; p += (size_t)N_NODES * D * 4;   // also holds residual before layer1 writes
    unsigned short* Wlh = (unsigned short*)p; p += (size_t)3 * D * D * 2;
    unsigned short* Wll = (unsigned short*)p; p += (size_t)3 * D * D * 2;
    unsigned short* Wrh = (unsigned short*)p; p += (size_t)3 * D * D * 2;
    unsigned short* Wrl = (unsigned short*)p; p += (size_t)3 * D * D * 2;
    unsigned short* pWh = (unsigned short*)p; p += (size_t)D * D * 2;
    unsigned short* pWl = (unsigned short*)p; p += (size_t)D * D * 2;
    int* deg     = (int*)p; p += (size_t)N_NODES * 4;
    float* invd  = (float*)p; p += (size_t)N_NODES * 4;
    int* offs    = (int*)p; p += (size_t)(N_NODES + 2) * 4;
    int* cursor  = (int*)p; p += (size_t)N_NODES * 4;
    int* csr_src = (int*)p; p += (size_t)N_EDGES * 4;
    int* bsums   = (int*)p; p += 512 * 4;

    const int* src = ei;
    const int* dst = ei + N_EDGES;

    // weight splits
    k_cvt_split<<<(3 * D * D / 4 + 255) / 256, 256, 0, stream>>>(WlAll, Wlh, Wll, 3 * D * D / 4);
    k_cvt_split<<<(3 * D * D / 4 + 255) / 256, 256, 0, stream>>>(WrAll, Wrh, Wrl, 3 * D * D / 4);
    k_cvt_split<<<(D * D / 4 + 255) / 256, 256, 0, stream>>>(projW, pWh, pWl, D * D / 4);

    // residual projection -> h1 (consumed by layer 0 before layer 1 overwrites h1)
    k_linear<<<N_NODES / 32, 256, 0, stream>>>(x, pWh, pWl, projB, h1);

    // CSR build
    hipMemsetAsync(deg, 0, (size_t)N_NODES * 4, stream);
    k_hist<<<(N_EDGES + 255) / 256, 256, 0, stream>>>(dst, deg);
    int nb = (N_NODES + 255) / 256;
    k_scan1<<<nb, 256, 0, stream>>>(deg, offs, bsums);
    k_scan2<<<1, 512, 0, stream>>>(bsums, nb);
    k_scan3<<<nb, 256, 0, stream>>>(deg, offs, bsums, cursor, invd);
    k_fill<<<(N_EDGES + 255) / 256, 256, 0, stream>>>(src, dst, cursor, csr_src);

    // layer 0 (h = x, skip = residual in h1)
    k_agg<<<N_NODES / 4, 256, 0, stream>>>(x, offs, csr_src, invd, agg);
    k_layer<<<N_NODES / 32, 256, 0, stream>>>(agg, x, h1, Wlh, Wll, Wrh, Wrl,
                                              lbAll, gAll, btAll, h0);
    // layer 1 (skip = h0)
    k_agg<<<N_NODES / 4, 256, 0, stream>>>(h0, offs, csr_src, invd, agg);
    k_layer<<<N_NODES / 32, 256, 0, stream>>>(agg, h0, h0,
                                              Wlh + D * D, Wll + D * D, Wrh + D * D, Wrl + D * D,
                                              lbAll + D, gAll + D, btAll + D, h1);
    // layer 2 (skip = h1)
    k_agg<<<N_NODES / 4, 256, 0, stream>>>(h1, offs, csr_src, invd, agg);
    k_layer<<<N_NODES / 32, 256, 0, stream>>>(agg, h1, h1,
                                              Wlh + 2 * D * D, Wll + 2 * D * D,
                                              Wrh + 2 * D * D, Wrl + 2 * D * D,
                                              lbAll + 2 * D, gAll + 2 * D, btAll + 2 * D, h0);

    k_head<<<N_NODES / 4, 256, 0, stream>>>(h0, hw, hbias, rr, alpha, out);
}

// Round 8
// 1137.482 us; speedup vs baseline: 1.8616x; 1.0534x over previous
//
#include <hip/hip_runtime.h>
#include <math.h>

#define N_NODES 100000
#define N_EDGES 1600000
#define D 128

typedef __attribute__((ext_vector_type(8))) short short8;
typedef __attribute__((ext_vector_type(4))) float floatx4;

__device__ __forceinline__ float bf2f(unsigned short u) {
    union { unsigned int i; float f; } v;
    v.i = ((unsigned int)u) << 16;
    return v.f;
}
__device__ __forceinline__ unsigned short f2bf(float f) {
    union { float f; unsigned int i; } v;
    v.f = f;
    unsigned int u = v.i;
    u += 0x7fffu + ((u >> 16) & 1u);
    return (unsigned short)(u >> 16);
}

// split 8 consecutive fp32 into hi/lo bf16 fragments (RNE) — in-register, R3-proven
__device__ __forceinline__ void split8(const float* __restrict__ p, short8& hi, short8& lo) {
    float4 v0 = *(const float4*)p;
    float4 v1 = *(const float4*)(p + 4);
    float f[8] = {v0.x, v0.y, v0.z, v0.w, v1.x, v1.y, v1.z, v1.w};
#pragma unroll
    for (int i = 0; i < 8; ++i) {
        unsigned short h = f2bf(f[i]);
        hi[i] = (short)h;
        lo[i] = (short)f2bf(f[i] - bf2f(h));
    }
}

__device__ __forceinline__ floatx4 mfma3(short8 ah, short8 al, short8 bh, short8 bl, floatx4 c) {
    c = __builtin_amdgcn_mfma_f32_16x16x32_bf16(ah, bh, c, 0, 0, 0);
    c = __builtin_amdgcn_mfma_f32_16x16x32_bf16(ah, bl, c, 0, 0, 0);
    c = __builtin_amdgcn_mfma_f32_16x16x32_bf16(al, bh, c, 0, 0, 0);
    return c;
}

// ---------------- weights: fp32 -> (hi,lo) bf16 RNE split (R3-proven) ----------------
__global__ void k_cvt_split(const float* __restrict__ s, unsigned short* __restrict__ hi,
                            unsigned short* __restrict__ lo, int n4) {
    int i = blockIdx.x * 256 + threadIdx.x;
    if (i < n4) {
        float4 v = ((const float4*)s)[i];
        float f[4] = {v.x, v.y, v.z, v.w};
        ushort4 h, l;
        unsigned short* hp = (unsigned short*)&h;
        unsigned short* lp = (unsigned short*)&l;
#pragma unroll
        for (int c = 0; c < 4; ++c) {
            unsigned short hh = f2bf(f[c]);
            hp[c] = hh;
            lp[c] = f2bf(f[c] - bf2f(hh));
        }
        ((ushort4*)hi)[i] = h;
        ((ushort4*)lo)[i] = l;
    }
}

// ---------------- CSR build (R3-proven) ----------------
__global__ void k_hist(const int* __restrict__ dst, int* __restrict__ deg) {
    int e = blockIdx.x * 256 + threadIdx.x;
    if (e < N_EDGES) atomicAdd(&deg[dst[e]], 1);
}

__global__ void k_scan1(const int* __restrict__ deg, int* __restrict__ offs,
                        int* __restrict__ bsums) {
    __shared__ int tmp[256];
    int tid = threadIdx.x;
    int i = blockIdx.x * 256 + tid;
    int v = (i < N_NODES) ? deg[i] : 0;
    tmp[tid] = v;
    __syncthreads();
    for (int off = 1; off < 256; off <<= 1) {
        int t = (tid >= off) ? tmp[tid - off] : 0;
        __syncthreads();
        if (tid >= off) tmp[tid] += t;
        __syncthreads();
    }
    if (i < N_NODES) offs[i] = tmp[tid] - v;
    if (tid == 255) bsums[blockIdx.x] = tmp[255];
}

__global__ void k_scan2(int* __restrict__ bsums, int nb) {
    __shared__ int tmp[512];
    int tid = threadIdx.x;
    int v = (tid < nb) ? bsums[tid] : 0;
    tmp[tid] = v;
    __syncthreads();
    for (int off = 1; off < 512; off <<= 1) {
        int t = (tid >= off) ? tmp[tid - off] : 0;
        __syncthreads();
        if (tid >= off) tmp[tid] += t;
        __syncthreads();
    }
    if (tid < nb) bsums[tid] = tmp[tid] - v;
}

__global__ void k_scan3(const int* __restrict__ deg, int* __restrict__ offs,
                        const int* __restrict__ bsums, int* __restrict__ cursor,
                        float* __restrict__ inv_deg) {
    int i = blockIdx.x * 256 + threadIdx.x;
    if (i < N_NODES) {
        int o = offs[i] + bsums[blockIdx.x];
        offs[i] = o;
        cursor[i] = o;
        int d = deg[i];
        inv_deg[i] = 1.0f / (float)(d > 1 ? d : 1);
        if (i == 0) offs[N_NODES] = N_EDGES;
    }
}

__global__ void k_fill(const int* __restrict__ src, const int* __restrict__ dst,
                       int* __restrict__ cursor, int* __restrict__ csr_src) {
    int e = blockIdx.x * 256 + threadIdx.x;
    if (e < N_EDGES) {
        int p = atomicAdd(&cursor[dst[e]], 1);
        csr_src[p] = src[e];
    }
}

// ---------------- mean aggregation (fp32 gather, bit-identical R3) ----------------
__global__ void k_agg(const float* __restrict__ h, const int* __restrict__ offs,
                      const int* __restrict__ csr_src, const float* __restrict__ inv_deg,
                      float* __restrict__ agg) {
    int node = blockIdx.x * 4 + (threadIdx.x >> 6);
    int lane = threadIdx.x & 63;
    int beg = offs[node], end = offs[node + 1];
    float ax = 0.f, ay = 0.f;
    for (int e = beg; e < end; ++e) {
        int s = csr_src[e];
        float2 v = ((const float2*)(h + (size_t)s * D))[lane];
        ax += v.x;
        ay += v.y;
    }
    float id = inv_deg[node];
    float2 o;
    o.x = ax * id;
    o.y = ay * id;
    ((float2*)(agg + (size_t)node * D))[lane] = o;
}

// ---------------- residual projection, 128-row blocks: res = x @ projW^T + projB ----
__global__ __launch_bounds__(256) void k_linear(
    const float* __restrict__ xf, const unsigned short* __restrict__ Wh,
    const unsigned short* __restrict__ Wl, const float* __restrict__ bias,
    float* __restrict__ outf) {
    int tid = threadIdx.x;
    int w = tid >> 6, lane = tid & 63;
    int quad = lane >> 4, l16 = lane & 15;
    int base = blockIdx.x * 128 + w * 32;

    int ar0 = base + l16; if (ar0 > N_NODES - 1) ar0 = N_NODES - 1;
    int ar1 = base + 16 + l16; if (ar1 > N_NODES - 1) ar1 = N_NODES - 1;
    const float* x0 = xf + (size_t)ar0 * D;
    const float* x1 = xf + (size_t)ar1 * D;
    int koff = quad * 8;

    floatx4 z = {0.f, 0.f, 0.f, 0.f};
    floatx4 acc[2][8];
#pragma unroll
    for (int rt = 0; rt < 2; ++rt)
#pragma unroll
        for (int ct = 0; ct < 8; ++ct) acc[rt][ct] = z;

#pragma unroll
    for (int ks = 0; ks < 4; ++ks) {
        int k0 = ks * 32 + koff;
        short8 a0h, a0l, a1h, a1l;
        split8(x0 + k0, a0h, a0l);
        split8(x1 + k0, a1h, a1l);
#pragma unroll
        for (int ct = 0; ct < 8; ++ct) {
            size_t nf = (size_t)(ct * 16 + l16) * D + k0;
            short8 wh = *(const short8*)(Wh + nf);
            short8 wl = *(const short8*)(Wl + nf);
            acc[0][ct] = mfma3(a0h, a0l, wh, wl, acc[0][ct]);
            acc[1][ct] = mfma3(a1h, a1l, wh, wl, acc[1][ct]);
        }
    }

    float bvv[8];
#pragma unroll
    for (int ct = 0; ct < 8; ++ct) bvv[ct] = bias[ct * 16 + l16];

#pragma unroll
    for (int rt = 0; rt < 2; ++rt)
#pragma unroll
        for (int r = 0; r < 4; ++r) {
            int crow = base + rt * 16 + quad * 4 + r;
            if (crow >= N_NODES) continue;
            size_t ro = (size_t)crow * D;
#pragma unroll
            for (int ct = 0; ct < 8; ++ct)
                outf[ro + ct * 16 + l16] = acc[rt][ct][r] + bvv[ct];
        }
}

// ---------------- fused SAGE layer, 128-row blocks, LDS-free LN ----------------
// h_out = LN(relu(agg@Wl^T + lb + h@Wr^T))*g + beta + skip   (all h/agg/skip fp32)
__global__ __launch_bounds__(256) void k_layer(
    const float* __restrict__ aggf, const float* __restrict__ hinf,
    const float* __restrict__ skipf,
    const unsigned short* __restrict__ Wlh, const unsigned short* __restrict__ Wll,
    const unsigned short* __restrict__ Wrh, const unsigned short* __restrict__ Wrl,
    const float* __restrict__ lb, const float* __restrict__ g,
    const float* __restrict__ beta, float* __restrict__ hout) {
    int tid = threadIdx.x;
    int w = tid >> 6, lane = tid & 63;
    int quad = lane >> 4, l16 = lane & 15;
    int base = blockIdx.x * 128 + w * 32;

    int ar0 = base + l16; if (ar0 > N_NODES - 1) ar0 = N_NODES - 1;
    int ar1 = base + 16 + l16; if (ar1 > N_NODES - 1) ar1 = N_NODES - 1;
    const float* agg0 = aggf + (size_t)ar0 * D;
    const float* agg1 = aggf + (size_t)ar1 * D;
    const float* hin0 = hinf + (size_t)ar0 * D;
    const float* hin1 = hinf + (size_t)ar1 * D;
    int koff = quad * 8;

    floatx4 z = {0.f, 0.f, 0.f, 0.f};
    floatx4 acc[2][8];
#pragma unroll
    for (int rt = 0; rt < 2; ++rt)
#pragma unroll
        for (int ct = 0; ct < 8; ++ct) acc[rt][ct] = z;

#pragma unroll
    for (int ks = 0; ks < 4; ++ks) {
        int k0 = ks * 32 + koff;
        short8 a0h, a0l, a1h, a1l, g0h, g0l, g1h, g1l;
        split8(agg0 + k0, a0h, a0l);
        split8(agg1 + k0, a1h, a1l);
        split8(hin0 + k0, g0h, g0l);
        split8(hin1 + k0, g1h, g1l);
#pragma unroll
        for (int ct = 0; ct < 8; ++ct) {
            size_t nf = (size_t)(ct * 16 + l16) * D + k0;
            short8 wlh = *(const short8*)(Wlh + nf);
            short8 wll = *(const short8*)(Wll + nf);
            short8 wrh = *(const short8*)(Wrh + nf);
            short8 wrl = *(const short8*)(Wrl + nf);
            acc[0][ct] = mfma3(a0h, a0l, wlh, wll, acc[0][ct]);
            acc[1][ct] = mfma3(a1h, a1l, wlh, wll, acc[1][ct]);
            acc[0][ct] = mfma3(g0h, g0l, wrh, wrl, acc[0][ct]);
            acc[1][ct] = mfma3(g1h, g1l, wrh, wrl, acc[1][ct]);
        }
    }

    // bias + relu in-register (y stored back into acc)
    float lbv[8], gv[8], bv[8];
#pragma unroll
    for (int ct = 0; ct < 8; ++ct) {
        int n = ct * 16 + l16;
        lbv[ct] = lb[n];
        gv[ct] = g[n];
        bv[ct] = beta[n];
    }
#pragma unroll
    for (int rt = 0; rt < 2; ++rt)
#pragma unroll
        for (int ct = 0; ct < 8; ++ct)
#pragma unroll
            for (int r = 0; r < 4; ++r)
                acc[rt][ct][r] = fmaxf(acc[rt][ct][r] + lbv[ct], 0.f);

    // LN stats per row, fully in-register: reduce over ct (8) then over the 16-lane group
    float mu[2][4], rs[2][4];
#pragma unroll
    for (int rt = 0; rt < 2; ++rt)
#pragma unroll
        for (int r = 0; r < 4; ++r) {
            float s = 0.f, ss = 0.f;
#pragma unroll
            for (int ct = 0; ct < 8; ++ct) {
                float v = acc[rt][ct][r];
                s += v;
                ss += v * v;
            }
#pragma unroll
            for (int m = 1; m < 16; m <<= 1) {
                s += __shfl_xor(s, m, 64);
                ss += __shfl_xor(ss, m, 64);
            }
            float m_ = s * (1.0f / 128.0f);
            float v_ = ss * (1.0f / 128.0f) - m_ * m_;
            mu[rt][r] = m_;
            rs[rt][r] = rsqrtf(v_ + 1e-5f);
        }

    // epilogue: LN scale/shift + fp32 skip, fp32 store
#pragma unroll
    for (int rt = 0; rt < 2; ++rt)
#pragma unroll
        for (int r = 0; r < 4; ++r) {
            int crow = base + rt * 16 + quad * 4 + r;
            if (crow >= N_NODES) continue;
            float m_ = mu[rt][r], rs_ = rs[rt][r];
            size_t ro = (size_t)crow * D;
#pragma unroll
            for (int ct = 0; ct < 8; ++ct) {
                int col = ct * 16 + l16;
                float sk = skipf[ro + col];
                hout[ro + col] = (acc[rt][ct][r] - m_) * rs_ * gv[ct] + bv[ct] + sk;
            }
        }
}

// ---------------- head (fp32, R3-proven) ----------------
__global__ void k_head(const float* __restrict__ h, const float* __restrict__ hw,
                       const float* __restrict__ hb_bias, const float* __restrict__ rr,
                       const float* __restrict__ alpha, float* __restrict__ out) {
    int node = blockIdx.x * 4 + (threadIdx.x >> 6);
    int lane = threadIdx.x & 63;
    float2 w = ((const float2*)hw)[lane];
    float2 v = ((const float2*)(h + (size_t)node * D))[lane];
    float s = v.x * w.x + v.y * w.y;
#pragma unroll
    for (int off = 32; off > 0; off >>= 1) s += __shfl_down(s, off, 64);
    if (lane == 0) {
        float a = 1.0f / (1.0f + expf(-alpha[0]));
        out[node] = a * rr[node] + (1.0f - a) * (s + hb_bias[0]);
    }
}

// ---------------- launch ----------------
extern "C" void kernel_launch(void* const* d_in, const int* in_sizes, int n_in,
                              void* d_out, int out_size, void* d_ws, size_t ws_size,
                              hipStream_t stream) {
    const float* x     = (const float*)d_in[0];
    const int*   ei    = (const int*)d_in[1];
    const float* rr    = (const float*)d_in[2];
    const float* projW = (const float*)d_in[3];
    const float* projB = (const float*)d_in[4];
    const float* WlAll = (const float*)d_in[5];
    const float* lbAll = (const float*)d_in[6];
    const float* WrAll = (const float*)d_in[7];
    const float* gAll  = (const float*)d_in[8];
    const float* btAll = (const float*)d_in[9];
    const float* hw    = (const float*)d_in[10];
    const float* hbias = (const float*)d_in[11];
    const float* alpha = (const float*)d_in[12];
    float* out = (float*)d_out;

    char* p = (char*)d_ws;
    float* agg = (float*)p; p += (size_t)N_NODES * D * 4;
    float* h0  = (float*)p; p += (size_t)N_NODES * D * 4;
    float* h1  = (float*)p; p += (size_t)N_NODES * D * 4;   // also holds residual before layer1 writes
    unsigned short* Wlh = (unsigned short*)p; p += (size_t)3 * D * D * 2;
    unsigned short* Wll = (unsigned short*)p; p += (size_t)3 * D * D * 2;
    unsigned short* Wrh = (unsigned short*)p; p += (size_t)3 * D * D * 2;
    unsigned short* Wrl = (unsigned short*)p; p += (size_t)3 * D * D * 2;
    unsigned short* pWh = (unsigned short*)p; p += (size_t)D * D * 2;
    unsigned short* pWl = (unsigned short*)p; p += (size_t)D * D * 2;
    int* deg     = (int*)p; p += (size_t)N_NODES * 4;
    float* invd  = (float*)p; p += (size_t)N_NODES * 4;
    int* offs    = (int*)p; p += (size_t)(N_NODES + 2) * 4;
    int* cursor  = (int*)p; p += (size_t)N_NODES * 4;
    int* csr_src = (int*)p; p += (size_t)N_EDGES * 4;
    int* bsums   = (int*)p; p += 512 * 4;

    float* res = h1;   // consumed by layer 0 before layer 1 overwrites h1

    const int* src = ei;
    const int* dst = ei + N_EDGES;

    // weight splits (RNE, R3-proven)
    k_cvt_split<<<(3 * D * D / 4 + 255) / 256, 256, 0, stream>>>(WlAll, Wlh, Wll, 3 * D * D / 4);
    k_cvt_split<<<(3 * D * D / 4 + 255) / 256, 256, 0, stream>>>(WrAll, Wrh, Wrl, 3 * D * D / 4);
    k_cvt_split<<<(D * D / 4 + 255) / 256, 256, 0, stream>>>(projW, pWh, pWl, D * D / 4);

    // CSR build
    hipMemsetAsync(deg, 0, (size_t)N_NODES * 4, stream);
    k_hist<<<(N_EDGES + 255) / 256, 256, 0, stream>>>(dst, deg);
    int nb = (N_NODES + 255) / 256;
    k_scan1<<<nb, 256, 0, stream>>>(deg, offs, bsums);
    k_scan2<<<1, 512, 0, stream>>>(bsums, nb);
    k_scan3<<<nb, 256, 0, stream>>>(deg, offs, bsums, cursor, invd);
    k_fill<<<(N_EDGES + 255) / 256, 256, 0, stream>>>(src, dst, cursor, csr_src);

    int gl = (N_NODES + 127) / 128;   // 782

    // residual projection -> res (= h1)
    k_linear<<<gl, 256, 0, stream>>>(x, pWh, pWl, projB, res);

    // layer 0 (h = x, skip = res fp32)
    k_agg<<<N_NODES / 4, 256, 0, stream>>>(x, offs, csr_src, invd, agg);
    k_layer<<<gl, 256, 0, stream>>>(agg, x, res, Wlh, Wll, Wrh, Wrl,
                                    lbAll, gAll, btAll, h0);
    // layer 1 (skip = h0)
    k_agg<<<N_NODES / 4, 256, 0, stream>>>(h0, offs, csr_src, invd, agg);
    k_layer<<<gl, 256, 0, stream>>>(agg, h0, h0,
                                    Wlh + D * D, Wll + D * D, Wrh + D * D, Wrl + D * D,
                                    lbAll + D, gAll + D, btAll + D, h1);
    // layer 2 (skip = h1)
    k_agg<<<N_NODES / 4, 256, 0, stream>>>(h1, offs, csr_src, invd, agg);
    k_layer<<<gl, 256, 0, stream>>>(agg, h1, h1,
                                    Wlh + 2 * D * D, Wll + 2 * D * D,
                                    Wrh + 2 * D * D, Wrl + 2 * D * D,
                                    lbAll + 2 * D, gAll + 2 * D, btAll + 2 * D, h0);

    k_head<<<N_NODES / 4, 256, 0, stream>>>(h0, hw, hbias, rr, alpha, out);
}

// Round 9
// 873.607 us; speedup vs baseline: 2.4239x; 1.3021x over previous
//
#include <hip/hip_runtime.h>
#include <math.h>

#define N_NODES 100000
#define N_EDGES 1600000
#define D 128

typedef __attribute__((ext_vector_type(8))) short short8;
typedef __attribute__((ext_vector_type(4))) float floatx4;

__device__ __forceinline__ float bf2f(unsigned short u) {
    union { unsigned int i; float f; } v;
    v.i = ((unsigned int)u) << 16;
    return v.f;
}
__device__ __forceinline__ unsigned short f2bf(float f) {
    union { float f; unsigned int i; } v;
    v.f = f;
    unsigned int u = v.i;
    u += 0x7fffu + ((u >> 16) & 1u);
    return (unsigned short)(u >> 16);
}
__device__ __forceinline__ unsigned short f2h(float f) {
    union { _Float16 h; unsigned short u; } c;
    c.h = (_Float16)f;
    return c.u;
}
__device__ __forceinline__ float h2f(unsigned short u) {
    union { unsigned short u; _Float16 h; } c;
    c.u = u;
    return (float)c.h;
}

// split 8 consecutive fp32 into hi/lo bf16 fragments (RNE) — in-register, R3/R8-proven
__device__ __forceinline__ void split8(const float* __restrict__ p, short8& hi, short8& lo) {
    float4 v0 = *(const float4*)p;
    float4 v1 = *(const float4*)(p + 4);
    float f[8] = {v0.x, v0.y, v0.z, v0.w, v1.x, v1.y, v1.z, v1.w};
#pragma unroll
    for (int i = 0; i < 8; ++i) {
        unsigned short h = f2bf(f[i]);
        hi[i] = (short)h;
        lo[i] = (short)f2bf(f[i] - bf2f(h));
    }
}

__device__ __forceinline__ floatx4 mfma3(short8 ah, short8 al, short8 bh, short8 bl, floatx4 c) {
    c = __builtin_amdgcn_mfma_f32_16x16x32_bf16(ah, bh, c, 0, 0, 0);
    c = __builtin_amdgcn_mfma_f32_16x16x32_bf16(ah, bl, c, 0, 0, 0);
    c = __builtin_amdgcn_mfma_f32_16x16x32_bf16(al, bh, c, 0, 0, 0);
    return c;
}

// ---------------- weights: fp32 -> (hi,lo) bf16 RNE split ----------------
__global__ void k_cvt_split(const float* __restrict__ s, unsigned short* __restrict__ hi,
                            unsigned short* __restrict__ lo, int n4) {
    int i = blockIdx.x * 256 + threadIdx.x;
    if (i < n4) {
        float4 v = ((const float4*)s)[i];
        float f[4] = {v.x, v.y, v.z, v.w};
        ushort4 h, l;
        unsigned short* hp = (unsigned short*)&h;
        unsigned short* lp = (unsigned short*)&l;
#pragma unroll
        for (int c = 0; c < 4; ++c) {
            unsigned short hh = f2bf(f[c]);
            hp[c] = hh;
            lp[c] = f2bf(f[c] - bf2f(hh));
        }
        ((ushort4*)hi)[i] = h;
        ((ushort4*)lo)[i] = l;
    }
}

// ---------------- x: fp32 -> fp16 (gather copy only) ----------------
__global__ void k_cvt_f16(const float* __restrict__ s, unsigned short* __restrict__ d, int n4) {
    int i = blockIdx.x * 256 + threadIdx.x;
    if (i < n4) {
        float4 v = ((const float4*)s)[i];
        ushort4 o;
        o.x = f2h(v.x); o.y = f2h(v.y); o.z = f2h(v.z); o.w = f2h(v.w);
        ((ushort4*)d)[i] = o;
    }
}

// ---------------- CSR build (R3-proven) ----------------
__global__ void k_hist(const int* __restrict__ dst, int* __restrict__ deg) {
    int e = blockIdx.x * 256 + threadIdx.x;
    if (e < N_EDGES) atomicAdd(&deg[dst[e]], 1);
}

__global__ void k_scan1(const int* __restrict__ deg, int* __restrict__ offs,
                        int* __restrict__ bsums) {
    __shared__ int tmp[256];
    int tid = threadIdx.x;
    int i = blockIdx.x * 256 + tid;
    int v = (i < N_NODES) ? deg[i] : 0;
    tmp[tid] = v;
    __syncthreads();
    for (int off = 1; off < 256; off <<= 1) {
        int t = (tid >= off) ? tmp[tid - off] : 0;
        __syncthreads();
        if (tid >= off) tmp[tid] += t;
        __syncthreads();
    }
    if (i < N_NODES) offs[i] = tmp[tid] - v;
    if (tid == 255) bsums[blockIdx.x] = tmp[255];
}

__global__ void k_scan2(int* __restrict__ bsums, int nb) {
    __shared__ int tmp[512];
    int tid = threadIdx.x;
    int v = (tid < nb) ? bsums[tid] : 0;
    tmp[tid] = v;
    __syncthreads();
    for (int off = 1; off < 512; off <<= 1) {
        int t = (tid >= off) ? tmp[tid - off] : 0;
        __syncthreads();
        if (tid >= off) tmp[tid] += t;
        __syncthreads();
    }
    if (tid < nb) bsums[tid] = tmp[tid] - v;
}

__global__ void k_scan3(const int* __restrict__ deg, int* __restrict__ offs,
                        const int* __restrict__ bsums, int* __restrict__ cursor,
                        float* __restrict__ inv_deg) {
    int i = blockIdx.x * 256 + threadIdx.x;
    if (i < N_NODES) {
        int o = offs[i] + bsums[blockIdx.x];
        offs[i] = o;
        cursor[i] = o;
        int d = deg[i];
        inv_deg[i] = 1.0f / (float)(d > 1 ? d : 1);
        if (i == 0) offs[N_NODES] = N_EDGES;
    }
}

__global__ void k_fill(const int* __restrict__ src, const int* __restrict__ dst,
                       int* __restrict__ cursor, int* __restrict__ csr_src) {
    int e = blockIdx.x * 256 + threadIdx.x;
    if (e < N_EDGES) {
        int p = atomicAdd(&cursor[dst[e]], 1);
        csr_src[p] = src[e];
    }
}

// ---------------- mean aggregation: gather fp16 rows -> fp32 agg ----------------
// one wave per node; lane holds 2 fp16 (one uint) of the 128-col row; ×4 unroll for MLP
__global__ void k_agg_f16(const unsigned short* __restrict__ hf, const int* __restrict__ offs,
                          const int* __restrict__ csr_src, const float* __restrict__ inv_deg,
                          float* __restrict__ agg) {
    int node = blockIdx.x * 4 + (threadIdx.x >> 6);
    int lane = threadIdx.x & 63;
    int beg = offs[node], end = offs[node + 1];
    float ax = 0.f, ay = 0.f;
    int e = beg;
    for (; e + 3 < end; e += 4) {
        int s0 = csr_src[e], s1 = csr_src[e + 1], s2 = csr_src[e + 2], s3 = csr_src[e + 3];
        unsigned int v0 = ((const unsigned int*)(hf + (size_t)s0 * D))[lane];
        unsigned int v1 = ((const unsigned int*)(hf + (size_t)s1 * D))[lane];
        unsigned int v2 = ((const unsigned int*)(hf + (size_t)s2 * D))[lane];
        unsigned int v3 = ((const unsigned int*)(hf + (size_t)s3 * D))[lane];
        ax += h2f((unsigned short)(v0 & 0xffffu)) + h2f((unsigned short)(v1 & 0xffffu)) +
              h2f((unsigned short)(v2 & 0xffffu)) + h2f((unsigned short)(v3 & 0xffffu));
        ay += h2f((unsigned short)(v0 >> 16)) + h2f((unsigned short)(v1 >> 16)) +
              h2f((unsigned short)(v2 >> 16)) + h2f((unsigned short)(v3 >> 16));
    }
    for (; e < end; ++e) {
        int s = csr_src[e];
        unsigned int v = ((const unsigned int*)(hf + (size_t)s * D))[lane];
        ax += h2f((unsigned short)(v & 0xffffu));
        ay += h2f((unsigned short)(v >> 16));
    }
    float id = inv_deg[node];
    float2 o;
    o.x = ax * id;
    o.y = ay * id;
    ((float2*)(agg + (size_t)node * D))[lane] = o;
}

// ---------------- fused SAGE layer, 128-row blocks, LDS-free LN (R8 structure) ------
// MODE 0: + fused residual projection (skip = x@projW^T+projB), writes hout + houtf16
// MODE 1: skip = skipf (fp32), writes hout + houtf16
// MODE 2: skip = skipf; fused head: out = a*rr + (1-a)*(h·hw + hb); no h writes
template <int MODE>
__global__ __launch_bounds__(256) void k_layer(
    const float* __restrict__ aggf, const float* __restrict__ hinf,
    const float* __restrict__ skipf,
    const unsigned short* __restrict__ Wlh, const unsigned short* __restrict__ Wll,
    const unsigned short* __restrict__ Wrh, const unsigned short* __restrict__ Wrl,
    const unsigned short* __restrict__ pWh, const unsigned short* __restrict__ pWl,
    const float* __restrict__ projB,
    const float* __restrict__ lb, const float* __restrict__ g,
    const float* __restrict__ beta,
    float* __restrict__ hout, unsigned short* __restrict__ houtf,
    const float* __restrict__ hw, const float* __restrict__ hb_bias,
    const float* __restrict__ rr, const float* __restrict__ alphap,
    float* __restrict__ outp) {
    int tid = threadIdx.x;
    int w = tid >> 6, lane = tid & 63;
    int quad = lane >> 4, l16 = lane & 15;
    int base = blockIdx.x * 128 + w * 32;

    int ar0 = base + l16; if (ar0 > N_NODES - 1) ar0 = N_NODES - 1;
    int ar1 = base + 16 + l16; if (ar1 > N_NODES - 1) ar1 = N_NODES - 1;
    const float* agg0 = aggf + (size_t)ar0 * D;
    const float* agg1 = aggf + (size_t)ar1 * D;
    const float* hin0 = hinf + (size_t)ar0 * D;
    const float* hin1 = hinf + (size_t)ar1 * D;
    int koff = quad * 8;

    floatx4 z = {0.f, 0.f, 0.f, 0.f};
    floatx4 acc[2][8];
    floatx4 accR[2][8];
#pragma unroll
    for (int rt = 0; rt < 2; ++rt)
#pragma unroll
        for (int ct = 0; ct < 8; ++ct) { acc[rt][ct] = z; if (MODE == 0) accR[rt][ct] = z; }

#pragma unroll
    for (int ks = 0; ks < 4; ++ks) {
        int k0 = ks * 32 + koff;
        short8 a0h, a0l, a1h, a1l, g0h, g0l, g1h, g1l;
        split8(agg0 + k0, a0h, a0l);
        split8(agg1 + k0, a1h, a1l);
        split8(hin0 + k0, g0h, g0l);
        split8(hin1 + k0, g1h, g1l);
#pragma unroll
        for (int ct = 0; ct < 8; ++ct) {
            size_t nf = (size_t)(ct * 16 + l16) * D + k0;
            short8 wlh = *(const short8*)(Wlh + nf);
            short8 wll = *(const short8*)(Wll + nf);
            short8 wrh = *(const short8*)(Wrh + nf);
            short8 wrl = *(const short8*)(Wrl + nf);
            acc[0][ct] = mfma3(a0h, a0l, wlh, wll, acc[0][ct]);
            acc[1][ct] = mfma3(a1h, a1l, wlh, wll, acc[1][ct]);
            acc[0][ct] = mfma3(g0h, g0l, wrh, wrl, acc[0][ct]);
            acc[1][ct] = mfma3(g1h, g1l, wrh, wrl, acc[1][ct]);
            if (MODE == 0) {
                short8 ph = *(const short8*)(pWh + nf);
                short8 pl = *(const short8*)(pWl + nf);
                accR[0][ct] = mfma3(g0h, g0l, ph, pl, accR[0][ct]);
                accR[1][ct] = mfma3(g1h, g1l, ph, pl, accR[1][ct]);
            }
        }
    }

    // bias + relu in-register
    float lbv[8], gv[8], bv[8];
#pragma unroll
    for (int ct = 0; ct < 8; ++ct) {
        int n = ct * 16 + l16;
        lbv[ct] = lb[n];
        gv[ct] = g[n];
        bv[ct] = beta[n];
    }
#pragma unroll
    for (int rt = 0; rt < 2; ++rt)
#pragma unroll
        for (int ct = 0; ct < 8; ++ct)
#pragma unroll
            for (int r = 0; r < 4; ++r)
                acc[rt][ct][r] = fmaxf(acc[rt][ct][r] + lbv[ct], 0.f);

    // LN stats per row, in-register: reduce over ct then the 16-lane group
    float mu[2][4], rs[2][4];
#pragma unroll
    for (int rt = 0; rt < 2; ++rt)
#pragma unroll
        for (int r = 0; r < 4; ++r) {
            float s = 0.f, ss = 0.f;
#pragma unroll
            for (int ct = 0; ct < 8; ++ct) {
                float v = acc[rt][ct][r];
                s += v;
                ss += v * v;
            }
#pragma unroll
            for (int m = 1; m < 16; m <<= 1) {
                s += __shfl_xor(s, m, 64);
                ss += __shfl_xor(ss, m, 64);
            }
            float m_ = s * (1.0f / 128.0f);
            float v_ = ss * (1.0f / 128.0f) - m_ * m_;
            mu[rt][r] = m_;
            rs[rt][r] = rsqrtf(v_ + 1e-5f);
        }

    float pbv[8], hwv[8];
    if (MODE == 0) {
#pragma unroll
        for (int ct = 0; ct < 8; ++ct) pbv[ct] = projB[ct * 16 + l16];
    }
    if (MODE == 2) {
#pragma unroll
        for (int ct = 0; ct < 8; ++ct) hwv[ct] = hw[ct * 16 + l16];
    }

    // epilogue
#pragma unroll
    for (int rt = 0; rt < 2; ++rt)
#pragma unroll
        for (int r = 0; r < 4; ++r) {
            int crow = base + rt * 16 + quad * 4 + r;
            bool valid = (crow < N_NODES);
            float m_ = mu[rt][r], rs_ = rs[rt][r];
            size_t ro = (size_t)crow * D;
            if (MODE == 2) {
                float s = 0.f;
#pragma unroll
                for (int ct = 0; ct < 8; ++ct) {
                    int col = ct * 16 + l16;
                    float sk = valid ? skipf[ro + col] : 0.f;
                    float o = (acc[rt][ct][r] - m_) * rs_ * gv[ct] + bv[ct] + sk;
                    s += o * hwv[ct];
                }
#pragma unroll
                for (int m = 1; m < 16; m <<= 1) s += __shfl_xor(s, m, 64);
                if (l16 == 0 && valid) {
                    float a = 1.0f / (1.0f + expf(-alphap[0]));
                    outp[crow] = a * rr[crow] + (1.0f - a) * (s + hb_bias[0]);
                }
            } else {
                if (!valid) continue;
#pragma unroll
                for (int ct = 0; ct < 8; ++ct) {
                    int col = ct * 16 + l16;
                    float sk = (MODE == 0) ? (accR[rt][ct][r] + pbv[ct]) : skipf[ro + col];
                    float o = (acc[rt][ct][r] - m_) * rs_ * gv[ct] + bv[ct] + sk;
                    hout[ro + col] = o;
                    houtf[ro + col] = f2h(o);
                }
            }
        }
}

// ---------------- launch ----------------
extern "C" void kernel_launch(void* const* d_in, const int* in_sizes, int n_in,
                              void* d_out, int out_size, void* d_ws, size_t ws_size,
                              hipStream_t stream) {
    const float* x     = (const float*)d_in[0];
    const int*   ei    = (const int*)d_in[1];
    const float* rr    = (const float*)d_in[2];
    const float* projW = (const float*)d_in[3];
    const float* projB = (const float*)d_in[4];
    const float* WlAll = (const float*)d_in[5];
    const float* lbAll = (const float*)d_in[6];
    const float* WrAll = (const float*)d_in[7];
    const float* gAll  = (const float*)d_in[8];
    const float* btAll = (const float*)d_in[9];
    const float* hw    = (const float*)d_in[10];
    const float* hbias = (const float*)d_in[11];
    const float* alpha = (const float*)d_in[12];
    float* out = (float*)d_out;

    char* p = (char*)d_ws;
    float* agg = (float*)p; p += (size_t)N_NODES * D * 4;
    float* h0  = (float*)p; p += (size_t)N_NODES * D * 4;
    float* h1  = (float*)p; p += (size_t)N_NODES * D * 4;
    unsigned short* h0f = (unsigned short*)p; p += (size_t)N_NODES * D * 2;
    unsigned short* h1f = (unsigned short*)p; p += (size_t)N_NODES * D * 2;
    unsigned short* Wlh = (unsigned short*)p; p += (size_t)3 * D * D * 2;
    unsigned short* Wll = (unsigned short*)p; p += (size_t)3 * D * D * 2;
    unsigned short* Wrh = (unsigned short*)p; p += (size_t)3 * D * D * 2;
    unsigned short* Wrl = (unsigned short*)p; p += (size_t)3 * D * D * 2;
    unsigned short* pWh = (unsigned short*)p; p += (size_t)D * D * 2;
    unsigned short* pWl = (unsigned short*)p; p += (size_t)D * D * 2;
    int* deg     = (int*)p; p += (size_t)N_NODES * 4;
    float* invd  = (float*)p; p += (size_t)N_NODES * 4;
    int* offs    = (int*)p; p += (size_t)(N_NODES + 2) * 4;
    int* cursor  = (int*)p; p += (size_t)N_NODES * 4;
    int* csr_src = (int*)p; p += (size_t)N_EDGES * 4;
    int* bsums   = (int*)p; p += 512 * 4;

    // xf16 aliases h1: consumed by layer-0's k_agg, long before layer-1 writes h1
    unsigned short* xf = (unsigned short*)h1;

    const int* src = ei;
    const int* dst = ei + N_EDGES;

    // weight splits (RNE) + x fp16 copy
    k_cvt_split<<<(3 * D * D / 4 + 255) / 256, 256, 0, stream>>>(WlAll, Wlh, Wll, 3 * D * D / 4);
    k_cvt_split<<<(3 * D * D / 4 + 255) / 256, 256, 0, stream>>>(WrAll, Wrh, Wrl, 3 * D * D / 4);
    k_cvt_split<<<(D * D / 4 + 255) / 256, 256, 0, stream>>>(projW, pWh, pWl, D * D / 4);
    k_cvt_f16<<<(N_NODES * D / 4 + 255) / 256, 256, 0, stream>>>(x, xf, N_NODES * D / 4);

    // CSR build
    hipMemsetAsync(deg, 0, (size_t)N_NODES * 4, stream);
    k_hist<<<(N_EDGES + 255) / 256, 256, 0, stream>>>(dst, deg);
    int nb = (N_NODES + 255) / 256;
    k_scan1<<<nb, 256, 0, stream>>>(deg, offs, bsums);
    k_scan2<<<1, 512, 0, stream>>>(bsums, nb);
    k_scan3<<<nb, 256, 0, stream>>>(deg, offs, bsums, cursor, invd);
    k_fill<<<(N_EDGES + 255) / 256, 256, 0, stream>>>(src, dst, cursor, csr_src);

    int gl = (N_NODES + 127) / 128;   // 782

    // layer 0: h = x; skip = x@projW^T+projB fused in-kernel; writes h0 + h0f
    k_agg_f16<<<N_NODES / 4, 256, 0, stream>>>(xf, offs, csr_src, invd, agg);
    k_layer<0><<<gl, 256, 0, stream>>>(agg, x, nullptr,
                                       Wlh, Wll, Wrh, Wrl, pWh, pWl, projB,
                                       lbAll, gAll, btAll, h0, h0f,
                                       nullptr, nullptr, nullptr, nullptr, nullptr);
    // layer 1: h = h0, skip = h0; writes h1 + h1f
    k_agg_f16<<<N_NODES / 4, 256, 0, stream>>>(h0f, offs, csr_src, invd, agg);
    k_layer<1><<<gl, 256, 0, stream>>>(agg, h0, h0,
                                       Wlh + D * D, Wll + D * D, Wrh + D * D, Wrl + D * D,
                                       nullptr, nullptr, nullptr,
                                       lbAll + D, gAll + D, btAll + D, h1, h1f,
                                       nullptr, nullptr, nullptr, nullptr, nullptr);
    // layer 2: h = h1, skip = h1; fused head -> out
    k_agg_f16<<<N_NODES / 4, 256, 0, stream>>>(h1f, offs, csr_src, invd, agg);
    k_layer<2><<<gl, 256, 0, stream>>>(agg, h1, h1,
                                       Wlh + 2 * D * D, Wll + 2 * D * D,
                                       Wrh + 2 * D * D, Wrl + 2 * D * D,
                                       nullptr, nullptr, nullptr,
                                       lbAll + 2 * D, gAll + 2 * D, btAll + 2 * D,
                                       nullptr, nullptr,
                                       hw, hbias, rr, alpha, out);
}

// Round 10
// 760.972 us; speedup vs baseline: 2.7827x; 1.1480x over previous
//
#include <hip/hip_runtime.h>
#include <math.h>

#define N_NODES 100000
#define N_EDGES 1600000
#define D 128

typedef __attribute__((ext_vector_type(8))) short short8;
typedef __attribute__((ext_vector_type(4))) float floatx4;

__device__ __forceinline__ float bf2f(unsigned short u) {
    union { unsigned int i; float f; } v;
    v.i = ((unsigned int)u) << 16;
    return v.f;
}
__device__ __forceinline__ unsigned short f2bf(float f) {
    union { float f; unsigned int i; } v;
    v.f = f;
    unsigned int u = v.i;
    u += 0x7fffu + ((u >> 16) & 1u);
    return (unsigned short)(u >> 16);
}
__device__ __forceinline__ unsigned short f2h(float f) {
    union { _Float16 h; unsigned short u; } c;
    c.h = (_Float16)f;
    return c.u;
}
__device__ __forceinline__ float h2f(unsigned short u) {
    union { unsigned short u; _Float16 h; } c;
    c.u = u;
    return (float)c.h;
}

// split 8 consecutive fp32 into hi/lo bf16 fragments (RNE) — in-register, R3/R8-proven
__device__ __forceinline__ void split8(const float* __restrict__ p, short8& hi, short8& lo) {
    float4 v0 = *(const float4*)p;
    float4 v1 = *(const float4*)(p + 4);
    float f[8] = {v0.x, v0.y, v0.z, v0.w, v1.x, v1.y, v1.z, v1.w};
#pragma unroll
    for (int i = 0; i < 8; ++i) {
        unsigned short h = f2bf(f[i]);
        hi[i] = (short)h;
        lo[i] = (short)f2bf(f[i] - bf2f(h));
    }
}

__device__ __forceinline__ floatx4 mfma3(short8 ah, short8 al, short8 bh, short8 bl, floatx4 c) {
    c = __builtin_amdgcn_mfma_f32_16x16x32_bf16(ah, bh, c, 0, 0, 0);
    c = __builtin_amdgcn_mfma_f32_16x16x32_bf16(ah, bl, c, 0, 0, 0);
    c = __builtin_amdgcn_mfma_f32_16x16x32_bf16(al, bh, c, 0, 0, 0);
    return c;
}

// stage one weight pair (hi,lo) into LDS, fragment-major:
// entry e = (ct*4+ks)*64 + lane holds W[ct*16+(lane&15)][ks*32+(lane>>4)*8 .. +8]
__device__ __forceinline__ void stageW(unsigned short* sWh, unsigned short* sWl,
                                       const unsigned short* __restrict__ Wh,
                                       const unsigned short* __restrict__ Wl, int tid) {
#pragma unroll
    for (int i = 0; i < 8; ++i) {
        int e = tid + 256 * i;
        int ct = e >> 8;
        int ks = (e >> 6) & 3;
        int q = (e >> 4) & 3;
        int l16 = e & 15;
        size_t g = (size_t)(ct * 16 + l16) * D + ks * 32 + q * 8;
        *(uint4*)(sWh + (size_t)e * 8) = *(const uint4*)(Wh + g);
        *(uint4*)(sWl + (size_t)e * 8) = *(const uint4*)(Wl + g);
    }
}

// one GEMM pass over staged weights: acc[rt][ct] += split(A-rows) @ staged-W^T
__device__ __forceinline__ void gemm_pass(const float* __restrict__ r0, const float* __restrict__ r1,
                                          const unsigned short* sWh, const unsigned short* sWl,
                                          int lane, int koff, floatx4 acc[2][8]) {
#pragma unroll
    for (int ks = 0; ks < 4; ++ks) {
        int k0 = ks * 32 + koff;
        short8 a0h, a0l, a1h, a1l;
        split8(r0 + k0, a0h, a0l);
        split8(r1 + k0, a1h, a1l);
#pragma unroll
        for (int ct = 0; ct < 8; ++ct) {
            int eo = ((ct * 4 + ks) * 64 + lane) * 8;
            short8 wh = *(const short8*)(sWh + eo);
            short8 wl = *(const short8*)(sWl + eo);
            acc[0][ct] = mfma3(a0h, a0l, wh, wl, acc[0][ct]);
            acc[1][ct] = mfma3(a1h, a1l, wh, wl, acc[1][ct]);
        }
    }
}

// ---------------- weights: fp32 -> (hi,lo) bf16 RNE split ----------------
__global__ void k_cvt_split(const float* __restrict__ s, unsigned short* __restrict__ hi,
                            unsigned short* __restrict__ lo, int n4) {
    int i = blockIdx.x * 256 + threadIdx.x;
    if (i < n4) {
        float4 v = ((const float4*)s)[i];
        float f[4] = {v.x, v.y, v.z, v.w};
        ushort4 h, l;
        unsigned short* hp = (unsigned short*)&h;
        unsigned short* lp = (unsigned short*)&l;
#pragma unroll
        for (int c = 0; c < 4; ++c) {
            unsigned short hh = f2bf(f[c]);
            hp[c] = hh;
            lp[c] = f2bf(f[c] - bf2f(hh));
        }
        ((ushort4*)hi)[i] = h;
        ((ushort4*)lo)[i] = l;
    }
}

// ---------------- x: fp32 -> fp16 (gather copy only) ----------------
__global__ void k_cvt_f16(const float* __restrict__ s, unsigned short* __restrict__ d, int n4) {
    int i = blockIdx.x * 256 + threadIdx.x;
    if (i < n4) {
        float4 v = ((const float4*)s)[i];
        ushort4 o;
        o.x = f2h(v.x); o.y = f2h(v.y); o.z = f2h(v.z); o.w = f2h(v.w);
        ((ushort4*)d)[i] = o;
    }
}

// ---------------- CSR build (R3-proven) ----------------
__global__ void k_hist(const int* __restrict__ dst, int* __restrict__ deg) {
    int e = blockIdx.x * 256 + threadIdx.x;
    if (e < N_EDGES) atomicAdd(&deg[dst[e]], 1);
}

__global__ void k_scan1(const int* __restrict__ deg, int* __restrict__ offs,
                        int* __restrict__ bsums) {
    __shared__ int tmp[256];
    int tid = threadIdx.x;
    int i = blockIdx.x * 256 + tid;
    int v = (i < N_NODES) ? deg[i] : 0;
    tmp[tid] = v;
    __syncthreads();
    for (int off = 1; off < 256; off <<= 1) {
        int t = (tid >= off) ? tmp[tid - off] : 0;
        __syncthreads();
        if (tid >= off) tmp[tid] += t;
        __syncthreads();
    }
    if (i < N_NODES) offs[i] = tmp[tid] - v;
    if (tid == 255) bsums[blockIdx.x] = tmp[255];
}

__global__ void k_scan2(int* __restrict__ bsums, int nb) {
    __shared__ int tmp[512];
    int tid = threadIdx.x;
    int v = (tid < nb) ? bsums[tid] : 0;
    tmp[tid] = v;
    __syncthreads();
    for (int off = 1; off < 512; off <<= 1) {
        int t = (tid >= off) ? tmp[tid - off] : 0;
        __syncthreads();
        if (tid >= off) tmp[tid] += t;
        __syncthreads();
    }
    if (tid < nb) bsums[tid] = tmp[tid] - v;
}

__global__ void k_scan3(const int* __restrict__ deg, int* __restrict__ offs,
                        const int* __restrict__ bsums, int* __restrict__ cursor,
                        float* __restrict__ inv_deg) {
    int i = blockIdx.x * 256 + threadIdx.x;
    if (i < N_NODES) {
        int o = offs[i] + bsums[blockIdx.x];
        offs[i] = o;
        cursor[i] = o;
        int d = deg[i];
        inv_deg[i] = 1.0f / (float)(d > 1 ? d : 1);
        if (i == 0) offs[N_NODES] = N_EDGES;
    }
}

__global__ void k_fill(const int* __restrict__ src, const int* __restrict__ dst,
                       int* __restrict__ cursor, int* __restrict__ csr_src) {
    int e = blockIdx.x * 256 + threadIdx.x;
    if (e < N_EDGES) {
        int p = atomicAdd(&cursor[dst[e]], 1);
        csr_src[p] = src[e];
    }
}

// ---------------- mean aggregation: gather fp16 rows -> fp32 agg ----------------
__global__ void k_agg_f16(const unsigned short* __restrict__ hf, const int* __restrict__ offs,
                          const int* __restrict__ csr_src, const float* __restrict__ inv_deg,
                          float* __restrict__ agg) {
    int node = blockIdx.x * 4 + (threadIdx.x >> 6);
    int lane = threadIdx.x & 63;
    int beg = offs[node], end = offs[node + 1];
    float ax = 0.f, ay = 0.f;
    int e = beg;
    for (; e + 3 < end; e += 4) {
        int s0 = csr_src[e], s1 = csr_src[e + 1], s2 = csr_src[e + 2], s3 = csr_src[e + 3];
        unsigned int v0 = ((const unsigned int*)(hf + (size_t)s0 * D))[lane];
        unsigned int v1 = ((const unsigned int*)(hf + (size_t)s1 * D))[lane];
        unsigned int v2 = ((const unsigned int*)(hf + (size_t)s2 * D))[lane];
        unsigned int v3 = ((const unsigned int*)(hf + (size_t)s3 * D))[lane];
        ax += h2f((unsigned short)(v0 & 0xffffu)) + h2f((unsigned short)(v1 & 0xffffu)) +
              h2f((unsigned short)(v2 & 0xffffu)) + h2f((unsigned short)(v3 & 0xffffu));
        ay += h2f((unsigned short)(v0 >> 16)) + h2f((unsigned short)(v1 >> 16)) +
              h2f((unsigned short)(v2 >> 16)) + h2f((unsigned short)(v3 >> 16));
    }
    for (; e < end; ++e) {
        int s = csr_src[e];
        unsigned int v = ((const unsigned int*)(hf + (size_t)s * D))[lane];
        ax += h2f((unsigned short)(v & 0xffffu));
        ay += h2f((unsigned short)(v >> 16));
    }
    float id = inv_deg[node];
    float2 o;
    o.x = ax * id;
    o.y = ay * id;
    ((float2*)(agg + (size_t)node * D))[lane] = o;
}

// ---------------- fused SAGE layer, 128-row blocks, LDS-staged weights ----------------
// MODE 0: + fused residual projection (skip = x@projW^T+projB), writes hout + houtf16
// MODE 1: skip = skipf (fp32), writes hout + houtf16
// MODE 2: skip = skipf; fused head: out = a*rr + (1-a)*(h·hw + hb); no h writes
template <int MODE>
__global__ __launch_bounds__(256) void k_layer(
    const float* __restrict__ aggf, const float* __restrict__ hinf,
    const float* __restrict__ skipf,
    const unsigned short* __restrict__ Wlh, const unsigned short* __restrict__ Wll,
    const unsigned short* __restrict__ Wrh, const unsigned short* __restrict__ Wrl,
    const unsigned short* __restrict__ pWh, const unsigned short* __restrict__ pWl,
    const float* __restrict__ projB,
    const float* __restrict__ lb, const float* __restrict__ g,
    const float* __restrict__ beta,
    float* __restrict__ hout, unsigned short* __restrict__ houtf,
    const float* __restrict__ hw, const float* __restrict__ hb_bias,
    const float* __restrict__ rr, const float* __restrict__ alphap,
    float* __restrict__ outp) {
    __shared__ unsigned short sWh[16384];   // 32KB hi, fragment-major
    __shared__ unsigned short sWl[16384];   // 32KB lo

    int tid = threadIdx.x;
    int w = tid >> 6, lane = tid & 63;
    int quad = lane >> 4, l16 = lane & 15;
    int base = blockIdx.x * 128 + w * 32;

    int ar0 = base + l16; if (ar0 > N_NODES - 1) ar0 = N_NODES - 1;
    int ar1 = base + 16 + l16; if (ar1 > N_NODES - 1) ar1 = N_NODES - 1;
    const float* agg0 = aggf + (size_t)ar0 * D;
    const float* agg1 = aggf + (size_t)ar1 * D;
    const float* hin0 = hinf + (size_t)ar0 * D;
    const float* hin1 = hinf + (size_t)ar1 * D;
    int koff = quad * 8;

    floatx4 z = {0.f, 0.f, 0.f, 0.f};
    floatx4 acc[2][8];
#pragma unroll
    for (int rt = 0; rt < 2; ++rt)
#pragma unroll
        for (int ct = 0; ct < 8; ++ct) acc[rt][ct] = z;

    // pass 1: agg @ Wl^T
    stageW(sWh, sWl, Wlh, Wll, tid);
    __syncthreads();
    gemm_pass(agg0, agg1, sWh, sWl, lane, koff, acc);
    __syncthreads();

    // pass 2: hin @ Wr^T
    stageW(sWh, sWl, Wrh, Wrl, tid);
    __syncthreads();
    gemm_pass(hin0, hin1, sWh, sWl, lane, koff, acc);

    // pass 3 (layer 0 only): residual projection hin @ projW^T
    floatx4 accR[2][8];
    if (MODE == 0) {
#pragma unroll
        for (int rt = 0; rt < 2; ++rt)
#pragma unroll
            for (int ct = 0; ct < 8; ++ct) accR[rt][ct] = z;
        __syncthreads();
        stageW(sWh, sWl, pWh, pWl, tid);
        __syncthreads();
        gemm_pass(hin0, hin1, sWh, sWl, lane, koff, accR);
    }

    // bias + relu in-register
    float lbv[8], gv[8], bv[8];
#pragma unroll
    for (int ct = 0; ct < 8; ++ct) {
        int n = ct * 16 + l16;
        lbv[ct] = lb[n];
        gv[ct] = g[n];
        bv[ct] = beta[n];
    }
#pragma unroll
    for (int rt = 0; rt < 2; ++rt)
#pragma unroll
        for (int ct = 0; ct < 8; ++ct)
#pragma unroll
            for (int r = 0; r < 4; ++r)
                acc[rt][ct][r] = fmaxf(acc[rt][ct][r] + lbv[ct], 0.f);

    // LN stats per row, in-register
    float mu[2][4], rs[2][4];
#pragma unroll
    for (int rt = 0; rt < 2; ++rt)
#pragma unroll
        for (int r = 0; r < 4; ++r) {
            float s = 0.f, ss = 0.f;
#pragma unroll
            for (int ct = 0; ct < 8; ++ct) {
                float v = acc[rt][ct][r];
                s += v;
                ss += v * v;
            }
#pragma unroll
            for (int m = 1; m < 16; m <<= 1) {
                s += __shfl_xor(s, m, 64);
                ss += __shfl_xor(ss, m, 64);
            }
            float m_ = s * (1.0f / 128.0f);
            float v_ = ss * (1.0f / 128.0f) - m_ * m_;
            mu[rt][r] = m_;
            rs[rt][r] = rsqrtf(v_ + 1e-5f);
        }

    float pbv[8], hwv[8];
    if (MODE == 0) {
#pragma unroll
        for (int ct = 0; ct < 8; ++ct) pbv[ct] = projB[ct * 16 + l16];
    }
    if (MODE == 2) {
#pragma unroll
        for (int ct = 0; ct < 8; ++ct) hwv[ct] = hw[ct * 16 + l16];
    }

    // epilogue
#pragma unroll
    for (int rt = 0; rt < 2; ++rt)
#pragma unroll
        for (int r = 0; r < 4; ++r) {
            int crow = base + rt * 16 + quad * 4 + r;
            bool valid = (crow < N_NODES);
            float m_ = mu[rt][r], rs_ = rs[rt][r];
            size_t ro = (size_t)crow * D;
            if (MODE == 2) {
                float s = 0.f;
#pragma unroll
                for (int ct = 0; ct < 8; ++ct) {
                    int col = ct * 16 + l16;
                    float sk = valid ? skipf[ro + col] : 0.f;
                    float o = (acc[rt][ct][r] - m_) * rs_ * gv[ct] + bv[ct] + sk;
                    s += o * hwv[ct];
                }
#pragma unroll
                for (int m = 1; m < 16; m <<= 1) s += __shfl_xor(s, m, 64);
                if (l16 == 0 && valid) {
                    float a = 1.0f / (1.0f + expf(-alphap[0]));
                    outp[crow] = a * rr[crow] + (1.0f - a) * (s + hb_bias[0]);
                }
            } else {
                if (!valid) continue;
#pragma unroll
                for (int ct = 0; ct < 8; ++ct) {
                    int col = ct * 16 + l16;
                    float sk = (MODE == 0) ? (accR[rt][ct][r] + pbv[ct]) : skipf[ro + col];
                    float o = (acc[rt][ct][r] - m_) * rs_ * gv[ct] + bv[ct] + sk;
                    hout[ro + col] = o;
                    houtf[ro + col] = f2h(o);
                }
            }
        }
}

// ---------------- launch ----------------
extern "C" void kernel_launch(void* const* d_in, const int* in_sizes, int n_in,
                              void* d_out, int out_size, void* d_ws, size_t ws_size,
                              hipStream_t stream) {
    const float* x     = (const float*)d_in[0];
    const int*   ei    = (const int*)d_in[1];
    const float* rr    = (const float*)d_in[2];
    const float* projW = (const float*)d_in[3];
    const float* projB = (const float*)d_in[4];
    const float* WlAll = (const float*)d_in[5];
    const float* lbAll = (const float*)d_in[6];
    const float* WrAll = (const float*)d_in[7];
    const float* gAll  = (const float*)d_in[8];
    const float* btAll = (const float*)d_in[9];
    const float* hw    = (const float*)d_in[10];
    const float* hbias = (const float*)d_in[11];
    const float* alpha = (const float*)d_in[12];
    float* out = (float*)d_out;

    char* p = (char*)d_ws;
    float* agg = (float*)p; p += (size_t)N_NODES * D * 4;
    float* h0  = (float*)p; p += (size_t)N_NODES * D * 4;
    float* h1  = (float*)p; p += (size_t)N_NODES * D * 4;
    unsigned short* h0f = (unsigned short*)p; p += (size_t)N_NODES * D * 2;
    unsigned short* h1f = (unsigned short*)p; p += (size_t)N_NODES * D * 2;
    unsigned short* Wlh = (unsigned short*)p; p += (size_t)3 * D * D * 2;
    unsigned short* Wll = (unsigned short*)p; p += (size_t)3 * D * D * 2;
    unsigned short* Wrh = (unsigned short*)p; p += (size_t)3 * D * D * 2;
    unsigned short* Wrl = (unsigned short*)p; p += (size_t)3 * D * D * 2;
    unsigned short* pWh = (unsigned short*)p; p += (size_t)D * D * 2;
    unsigned short* pWl = (unsigned short*)p; p += (size_t)D * D * 2;
    int* deg     = (int*)p; p += (size_t)N_NODES * 4;
    float* invd  = (float*)p; p += (size_t)N_NODES * 4;
    int* offs    = (int*)p; p += (size_t)(N_NODES + 2) * 4;
    int* cursor  = (int*)p; p += (size_t)N_NODES * 4;
    int* csr_src = (int*)p; p += (size_t)N_EDGES * 4;
    int* bsums   = (int*)p; p += 512 * 4;

    // xf16 aliases h1: consumed by layer-0's k_agg, long before layer-1 writes h1
    unsigned short* xf = (unsigned short*)h1;

    const int* src = ei;
    const int* dst = ei + N_EDGES;

    // weight splits (RNE) + x fp16 copy
    k_cvt_split<<<(3 * D * D / 4 + 255) / 256, 256, 0, stream>>>(WlAll, Wlh, Wll, 3 * D * D / 4);
    k_cvt_split<<<(3 * D * D / 4 + 255) / 256, 256, 0, stream>>>(WrAll, Wrh, Wrl, 3 * D * D / 4);
    k_cvt_split<<<(D * D / 4 + 255) / 256, 256, 0, stream>>>(projW, pWh, pWl, D * D / 4);
    k_cvt_f16<<<(N_NODES * D / 4 + 255) / 256, 256, 0, stream>>>(x, xf, N_NODES * D / 4);

    // CSR build
    hipMemsetAsync(deg, 0, (size_t)N_NODES * 4, stream);
    k_hist<<<(N_EDGES + 255) / 256, 256, 0, stream>>>(dst, deg);
    int nb = (N_NODES + 255) / 256;
    k_scan1<<<nb, 256, 0, stream>>>(deg, offs, bsums);
    k_scan2<<<1, 512, 0, stream>>>(bsums, nb);
    k_scan3<<<nb, 256, 0, stream>>>(deg, offs, bsums, cursor, invd);
    k_fill<<<(N_EDGES + 255) / 256, 256, 0, stream>>>(src, dst, cursor, csr_src);

    int gl = (N_NODES + 127) / 128;   // 782

    // layer 0: h = x; skip = x@projW^T+projB fused in-kernel; writes h0 + h0f
    k_agg_f16<<<N_NODES / 4, 256, 0, stream>>>(xf, offs, csr_src, invd, agg);
    k_layer<0><<<gl, 256, 0, stream>>>(agg, x, nullptr,
                                       Wlh, Wll, Wrh, Wrl, pWh, pWl, projB,
                                       lbAll, gAll, btAll, h0, h0f,
                                       nullptr, nullptr, nullptr, nullptr, nullptr);
    // layer 1: h = h0, skip = h0; writes h1 + h1f
    k_agg_f16<<<N_NODES / 4, 256, 0, stream>>>(h0f, offs, csr_src, invd, agg);
    k_layer<1><<<gl, 256, 0, stream>>>(agg, h0, h0,
                                       Wlh + D * D, Wll + D * D, Wrh + D * D, Wrl + D * D,
                                       nullptr, nullptr, nullptr,
                                       lbAll + D, gAll + D, btAll + D, h1, h1f,
                                       nullptr, nullptr, nullptr, nullptr, nullptr);
    // layer 2: h = h1, skip = h1; fused head -> out
    k_agg_f16<<<N_NODES / 4, 256, 0, stream>>>(h1f, offs, csr_src, invd, agg);
    k_layer<2><<<gl, 256, 0, stream>>>(agg, h1, h1,
                                       Wlh + 2 * D * D, Wll + 2 * D * D,
                                       Wrh + 2 * D * D, Wrl + 2 * D * D,
                                       nullptr, nullptr, nullptr,
                                       lbAll + 2 * D, gAll + 2 * D, btAll + 2 * D,
                                       nullptr, nullptr,
                                       hw, hbias, rr, alpha, out);
}

// Round 11
// 681.996 us; speedup vs baseline: 3.1049x; 1.1158x over previous
//
#include <hip/hip_runtime.h>
#include <math.h>

#define N_NODES 100000
#define N_EDGES 1600000
#define D 128
#define NBKT 391   // ceil(N_NODES/256) buckets of 256 dst nodes

typedef __attribute__((ext_vector_type(8))) short short8;
typedef __attribute__((ext_vector_type(4))) float floatx4;

__device__ __forceinline__ float bf2f(unsigned short u) {
    union { unsigned int i; float f; } v;
    v.i = ((unsigned int)u) << 16;
    return v.f;
}
__device__ __forceinline__ unsigned short f2bf(float f) {
    union { float f; unsigned int i; } v;
    v.f = f;
    unsigned int u = v.i;
    u += 0x7fffu + ((u >> 16) & 1u);
    return (unsigned short)(u >> 16);
}
__device__ __forceinline__ unsigned short f2h(float f) {
    union { _Float16 h; unsigned short u; } c;
    c.h = (_Float16)f;
    return c.u;
}
__device__ __forceinline__ float h2f(unsigned short u) {
    union { unsigned short u; _Float16 h; } c;
    c.u = u;
    return (float)c.h;
}

// split 8 consecutive fp32 into hi/lo bf16 fragments (RNE) — in-register, R3/R8-proven
__device__ __forceinline__ void split8(const float* __restrict__ p, short8& hi, short8& lo) {
    float4 v0 = *(const float4*)p;
    float4 v1 = *(const float4*)(p + 4);
    float f[8] = {v0.x, v0.y, v0.z, v0.w, v1.x, v1.y, v1.z, v1.w};
#pragma unroll
    for (int i = 0; i < 8; ++i) {
        unsigned short h = f2bf(f[i]);
        hi[i] = (short)h;
        lo[i] = (short)f2bf(f[i] - bf2f(h));
    }
}

__device__ __forceinline__ floatx4 mfma3(short8 ah, short8 al, short8 bh, short8 bl, floatx4 c) {
    c = __builtin_amdgcn_mfma_f32_16x16x32_bf16(ah, bh, c, 0, 0, 0);
    c = __builtin_amdgcn_mfma_f32_16x16x32_bf16(ah, bl, c, 0, 0, 0);
    c = __builtin_amdgcn_mfma_f32_16x16x32_bf16(al, bh, c, 0, 0, 0);
    return c;
}

// stage one weight pair (hi,lo) into LDS, fragment-major
__device__ __forceinline__ void stageW(unsigned short* sWh, unsigned short* sWl,
                                       const unsigned short* __restrict__ Wh,
                                       const unsigned short* __restrict__ Wl, int tid) {
#pragma unroll
    for (int i = 0; i < 8; ++i) {
        int e = tid + 256 * i;
        int ct = e >> 8;
        int ks = (e >> 6) & 3;
        int q = (e >> 4) & 3;
        int l16 = e & 15;
        size_t g = (size_t)(ct * 16 + l16) * D + ks * 32 + q * 8;
        *(uint4*)(sWh + (size_t)e * 8) = *(const uint4*)(Wh + g);
        *(uint4*)(sWl + (size_t)e * 8) = *(const uint4*)(Wl + g);
    }
}

// one GEMM pass over staged weights
__device__ __forceinline__ void gemm_pass(const float* __restrict__ r0, const float* __restrict__ r1,
                                          const unsigned short* sWh, const unsigned short* sWl,
                                          int lane, int koff, floatx4 acc[2][8]) {
#pragma unroll
    for (int ks = 0; ks < 4; ++ks) {
        int k0 = ks * 32 + koff;
        short8 a0h, a0l, a1h, a1l;
        split8(r0 + k0, a0h, a0l);
        split8(r1 + k0, a1h, a1l);
#pragma unroll
        for (int ct = 0; ct < 8; ++ct) {
            int eo = ((ct * 4 + ks) * 64 + lane) * 8;
            short8 wh = *(const short8*)(sWh + eo);
            short8 wl = *(const short8*)(sWl + eo);
            acc[0][ct] = mfma3(a0h, a0l, wh, wl, acc[0][ct]);
            acc[1][ct] = mfma3(a1h, a1l, wh, wl, acc[1][ct]);
        }
    }
}

// ---------------- weights: fp32 -> (hi,lo) bf16 RNE split ----------------
__global__ void k_cvt_split(const float* __restrict__ s, unsigned short* __restrict__ hi,
                            unsigned short* __restrict__ lo, int n4) {
    int i = blockIdx.x * 256 + threadIdx.x;
    if (i < n4) {
        float4 v = ((const float4*)s)[i];
        float f[4] = {v.x, v.y, v.z, v.w};
        ushort4 h, l;
        unsigned short* hp = (unsigned short*)&h;
        unsigned short* lp = (unsigned short*)&l;
#pragma unroll
        for (int c = 0; c < 4; ++c) {
            unsigned short hh = f2bf(f[c]);
            hp[c] = hh;
            lp[c] = f2bf(f[c] - bf2f(hh));
        }
        ((ushort4*)hi)[i] = h;
        ((ushort4*)lo)[i] = l;
    }
}

// ---------------- x: fp32 -> fp16 (gather copy only) ----------------
__global__ void k_cvt_f16(const float* __restrict__ s, unsigned short* __restrict__ d, int n4) {
    int i = blockIdx.x * 256 + threadIdx.x;
    if (i < n4) {
        float4 v = ((const float4*)s)[i];
        ushort4 o;
        o.x = f2h(v.x); o.y = f2h(v.y); o.z = f2h(v.z); o.w = f2h(v.w);
        ((ushort4*)d)[i] = o;
    }
}

// ---------------- CSR build ----------------
__global__ void k_hist(const int* __restrict__ dst, int* __restrict__ deg) {
    int e = blockIdx.x * 256 + threadIdx.x;
    if (e < N_EDGES) atomicAdd(&deg[dst[e]], 1);
}

__global__ void k_scan1(const int* __restrict__ deg, int* __restrict__ offs,
                        int* __restrict__ bsums) {
    __shared__ int tmp[256];
    int tid = threadIdx.x;
    int i = blockIdx.x * 256 + tid;
    int v = (i < N_NODES) ? deg[i] : 0;
    tmp[tid] = v;
    __syncthreads();
    for (int off = 1; off < 256; off <<= 1) {
        int t = (tid >= off) ? tmp[tid - off] : 0;
        __syncthreads();
        if (tid >= off) tmp[tid] += t;
        __syncthreads();
    }
    if (i < N_NODES) offs[i] = tmp[tid] - v;
    if (tid == 255) bsums[blockIdx.x] = tmp[255];
}

__global__ void k_scan2(int* __restrict__ bsums, int nb) {
    __shared__ int tmp[512];
    int tid = threadIdx.x;
    int v = (tid < nb) ? bsums[tid] : 0;
    tmp[tid] = v;
    __syncthreads();
    for (int off = 1; off < 512; off <<= 1) {
        int t = (tid >= off) ? tmp[tid - off] : 0;
        __syncthreads();
        if (tid >= off) tmp[tid] += t;
        __syncthreads();
    }
    if (tid < nb) bsums[tid] = tmp[tid] - v;
}

__global__ void k_scan3(const int* __restrict__ deg, int* __restrict__ offs,
                        const int* __restrict__ bsums, int* __restrict__ cursor,
                        float* __restrict__ inv_deg) {
    int i = blockIdx.x * 256 + threadIdx.x;
    if (i < N_NODES) {
        int o = offs[i] + bsums[blockIdx.x];
        offs[i] = o;
        cursor[i] = o;
        int d = deg[i];
        inv_deg[i] = 1.0f / (float)(d > 1 ? d : 1);
        if (i == 0) offs[N_NODES] = N_EDGES;
    }
}

// bucket cursors = csr base of each 256-node bucket
__global__ void k_binit(const int* __restrict__ offs, int* __restrict__ bcur) {
    int b = blockIdx.x * 256 + threadIdx.x;
    if (b < NBKT) bcur[b] = offs[b << 8];
}

// pass A: scatter (src,dst) pairs bucket-contiguous (dst>>8 buckets)
__global__ __launch_bounds__(256) void k_bucket(const int* __restrict__ src,
                                                const int* __restrict__ dst,
                                                int* __restrict__ bcur, uint2* __restrict__ pairs) {
    __shared__ int cnt[NBKT];
    __shared__ int off[NBKT];
    int tid = threadIdx.x;
    for (int i = tid; i < NBKT; i += 256) cnt[i] = 0;
    __syncthreads();
    int e0 = blockIdx.x * 4096;
    int mydst[16], mysrc[16];
#pragma unroll
    for (int i = 0; i < 16; ++i) {
        int e = e0 + tid + i * 256;
        int d = (e < N_EDGES) ? dst[e] : -1;
        mydst[i] = d;
        mysrc[i] = (e < N_EDGES) ? src[e] : 0;
        if (d >= 0) atomicAdd(&cnt[d >> 8], 1);
    }
    __syncthreads();
    for (int b = tid; b < NBKT; b += 256) {
        int c = cnt[b];
        off[b] = c ? atomicAdd(&bcur[b], c) : 0;
    }
    __syncthreads();
#pragma unroll
    for (int i = 0; i < 16; ++i) {
        int d = mydst[i];
        if (d >= 0) {
            int p = atomicAdd(&off[d >> 8], 1);
            pairs[p] = make_uint2((unsigned)mysrc[i], (unsigned)d);
        }
    }
}

// pass B: one block per bucket — csr writes confined to one ~16KB region per block
__global__ __launch_bounds__(256) void k_fill2(const uint2* __restrict__ pairs,
                                               const int* __restrict__ offs,
                                               int* __restrict__ cursor, int* __restrict__ csr_src) {
    int b = blockIdx.x;
    int beg = offs[b << 8];
    int endn = (b + 1) << 8;
    if (endn > N_NODES) endn = N_NODES;
    int end = offs[endn];
    for (int e = beg + threadIdx.x; e < end; e += 256) {
        uint2 pr = pairs[e];
        int p = atomicAdd(&cursor[pr.y], 1);
        csr_src[p] = (int)pr.x;
    }
}

// ---------------- mean aggregation: gather fp16 rows -> fp32 agg (8-deep MLP) --------
__global__ void k_agg_f16(const unsigned short* __restrict__ hf, const int* __restrict__ offs,
                          const int* __restrict__ csr_src, const float* __restrict__ inv_deg,
                          float* __restrict__ agg) {
    int node = blockIdx.x * 4 + (threadIdx.x >> 6);
    int lane = threadIdx.x & 63;
    int beg = offs[node], end = offs[node + 1];
    float ax = 0.f, ay = 0.f;
    int e = beg;
    for (; e + 7 < end; e += 8) {
        int ss[8];
#pragma unroll
        for (int i = 0; i < 8; ++i) ss[i] = csr_src[e + i];
        unsigned int vv[8];
#pragma unroll
        for (int i = 0; i < 8; ++i)
            vv[i] = ((const unsigned int*)(hf + (size_t)ss[i] * D))[lane];
#pragma unroll
        for (int i = 0; i < 8; ++i) {
            ax += h2f((unsigned short)(vv[i] & 0xffffu));
            ay += h2f((unsigned short)(vv[i] >> 16));
        }
    }
    for (; e + 3 < end; e += 4) {
        int s0 = csr_src[e], s1 = csr_src[e + 1], s2 = csr_src[e + 2], s3 = csr_src[e + 3];
        unsigned int v0 = ((const unsigned int*)(hf + (size_t)s0 * D))[lane];
        unsigned int v1 = ((const unsigned int*)(hf + (size_t)s1 * D))[lane];
        unsigned int v2 = ((const unsigned int*)(hf + (size_t)s2 * D))[lane];
        unsigned int v3 = ((const unsigned int*)(hf + (size_t)s3 * D))[lane];
        ax += h2f((unsigned short)(v0 & 0xffffu)) + h2f((unsigned short)(v1 & 0xffffu)) +
              h2f((unsigned short)(v2 & 0xffffu)) + h2f((unsigned short)(v3 & 0xffffu));
        ay += h2f((unsigned short)(v0 >> 16)) + h2f((unsigned short)(v1 >> 16)) +
              h2f((unsigned short)(v2 >> 16)) + h2f((unsigned short)(v3 >> 16));
    }
    for (; e < end; ++e) {
        int s = csr_src[e];
        unsigned int v = ((const unsigned int*)(hf + (size_t)s * D))[lane];
        ax += h2f((unsigned short)(v & 0xffffu));
        ay += h2f((unsigned short)(v >> 16));
    }
    float id = inv_deg[node];
    float2 o;
    o.x = ax * id;
    o.y = ay * id;
    ((float2*)(agg + (size_t)node * D))[lane] = o;
}

// ---------------- fused SAGE layer, 128-row blocks, LDS-staged weights ----------------
template <int MODE>
__global__ __launch_bounds__(256) void k_layer(
    const float* __restrict__ aggf, const float* __restrict__ hinf,
    const float* __restrict__ skipf,
    const unsigned short* __restrict__ Wlh, const unsigned short* __restrict__ Wll,
    const unsigned short* __restrict__ Wrh, const unsigned short* __restrict__ Wrl,
    const unsigned short* __restrict__ pWh, const unsigned short* __restrict__ pWl,
    const float* __restrict__ projB,
    const float* __restrict__ lb, const float* __restrict__ g,
    const float* __restrict__ beta,
    float* __restrict__ hout, unsigned short* __restrict__ houtf,
    const float* __restrict__ hw, const float* __restrict__ hb_bias,
    const float* __restrict__ rr, const float* __restrict__ alphap,
    float* __restrict__ outp) {
    __shared__ unsigned short sWh[16384];
    __shared__ unsigned short sWl[16384];

    int tid = threadIdx.x;
    int w = tid >> 6, lane = tid & 63;
    int quad = lane >> 4, l16 = lane & 15;
    int base = blockIdx.x * 128 + w * 32;

    int ar0 = base + l16; if (ar0 > N_NODES - 1) ar0 = N_NODES - 1;
    int ar1 = base + 16 + l16; if (ar1 > N_NODES - 1) ar1 = N_NODES - 1;
    const float* agg0 = aggf + (size_t)ar0 * D;
    const float* agg1 = aggf + (size_t)ar1 * D;
    const float* hin0 = hinf + (size_t)ar0 * D;
    const float* hin1 = hinf + (size_t)ar1 * D;
    int koff = quad * 8;

    floatx4 z = {0.f, 0.f, 0.f, 0.f};
    floatx4 acc[2][8];
#pragma unroll
    for (int rt = 0; rt < 2; ++rt)
#pragma unroll
        for (int ct = 0; ct < 8; ++ct) acc[rt][ct] = z;

    stageW(sWh, sWl, Wlh, Wll, tid);
    __syncthreads();
    gemm_pass(agg0, agg1, sWh, sWl, lane, koff, acc);
    __syncthreads();

    stageW(sWh, sWl, Wrh, Wrl, tid);
    __syncthreads();
    gemm_pass(hin0, hin1, sWh, sWl, lane, koff, acc);

    floatx4 accR[2][8];
    if (MODE == 0) {
#pragma unroll
        for (int rt = 0; rt < 2; ++rt)
#pragma unroll
            for (int ct = 0; ct < 8; ++ct) accR[rt][ct] = z;
        __syncthreads();
        stageW(sWh, sWl, pWh, pWl, tid);
        __syncthreads();
        gemm_pass(hin0, hin1, sWh, sWl, lane, koff, accR);
    }

    float lbv[8], gv[8], bv[8];
#pragma unroll
    for (int ct = 0; ct < 8; ++ct) {
        int n = ct * 16 + l16;
        lbv[ct] = lb[n];
        gv[ct] = g[n];
        bv[ct] = beta[n];
    }
#pragma unroll
    for (int rt = 0; rt < 2; ++rt)
#pragma unroll
        for (int ct = 0; ct < 8; ++ct)
#pragma unroll
            for (int r = 0; r < 4; ++r)
                acc[rt][ct][r] = fmaxf(acc[rt][ct][r] + lbv[ct], 0.f);

    float mu[2][4], rs[2][4];
#pragma unroll
    for (int rt = 0; rt < 2; ++rt)
#pragma unroll
        for (int r = 0; r < 4; ++r) {
            float s = 0.f, ss = 0.f;
#pragma unroll
            for (int ct = 0; ct < 8; ++ct) {
                float v = acc[rt][ct][r];
                s += v;
                ss += v * v;
            }
#pragma unroll
            for (int m = 1; m < 16; m <<= 1) {
                s += __shfl_xor(s, m, 64);
                ss += __shfl_xor(ss, m, 64);
            }
            float m_ = s * (1.0f / 128.0f);
            float v_ = ss * (1.0f / 128.0f) - m_ * m_;
            mu[rt][r] = m_;
            rs[rt][r] = rsqrtf(v_ + 1e-5f);
        }

    float pbv[8], hwv[8];
    if (MODE == 0) {
#pragma unroll
        for (int ct = 0; ct < 8; ++ct) pbv[ct] = projB[ct * 16 + l16];
    }
    if (MODE == 2) {
#pragma unroll
        for (int ct = 0; ct < 8; ++ct) hwv[ct] = hw[ct * 16 + l16];
    }

#pragma unroll
    for (int rt = 0; rt < 2; ++rt)
#pragma unroll
        for (int r = 0; r < 4; ++r) {
            int crow = base + rt * 16 + quad * 4 + r;
            bool valid = (crow < N_NODES);
            float m_ = mu[rt][r], rs_ = rs[rt][r];
            size_t ro = (size_t)crow * D;
            if (MODE == 2) {
                float s = 0.f;
#pragma unroll
                for (int ct = 0; ct < 8; ++ct) {
                    int col = ct * 16 + l16;
                    float sk = valid ? skipf[ro + col] : 0.f;
                    float o = (acc[rt][ct][r] - m_) * rs_ * gv[ct] + bv[ct] + sk;
                    s += o * hwv[ct];
                }
#pragma unroll
                for (int m = 1; m < 16; m <<= 1) s += __shfl_xor(s, m, 64);
                if (l16 == 0 && valid) {
                    float a = 1.0f / (1.0f + expf(-alphap[0]));
                    outp[crow] = a * rr[crow] + (1.0f - a) * (s + hb_bias[0]);
                }
            } else {
                if (!valid) continue;
#pragma unroll
                for (int ct = 0; ct < 8; ++ct) {
                    int col = ct * 16 + l16;
                    float sk = (MODE == 0) ? (accR[rt][ct][r] + pbv[ct]) : skipf[ro + col];
                    float o = (acc[rt][ct][r] - m_) * rs_ * gv[ct] + bv[ct] + sk;
                    hout[ro + col] = o;
                    houtf[ro + col] = f2h(o);
                }
            }
        }
}

// ---------------- launch ----------------
extern "C" void kernel_launch(void* const* d_in, const int* in_sizes, int n_in,
                              void* d_out, int out_size, void* d_ws, size_t ws_size,
                              hipStream_t stream) {
    const float* x     = (const float*)d_in[0];
    const int*   ei    = (const int*)d_in[1];
    const float* rr    = (const float*)d_in[2];
    const float* projW = (const float*)d_in[3];
    const float* projB = (const float*)d_in[4];
    const float* WlAll = (const float*)d_in[5];
    const float* lbAll = (const float*)d_in[6];
    const float* WrAll = (const float*)d_in[7];
    const float* gAll  = (const float*)d_in[8];
    const float* btAll = (const float*)d_in[9];
    const float* hw    = (const float*)d_in[10];
    const float* hbias = (const float*)d_in[11];
    const float* alpha = (const float*)d_in[12];
    float* out = (float*)d_out;

    char* p = (char*)d_ws;
    float* agg = (float*)p; p += (size_t)N_NODES * D * 4;
    float* h0  = (float*)p; p += (size_t)N_NODES * D * 4;
    float* h1  = (float*)p; p += (size_t)N_NODES * D * 4;
    unsigned short* h0f = (unsigned short*)p; p += (size_t)N_NODES * D * 2;
    unsigned short* h1f = (unsigned short*)p; p += (size_t)N_NODES * D * 2;
    unsigned short* Wlh = (unsigned short*)p; p += (size_t)3 * D * D * 2;
    unsigned short* Wll = (unsigned short*)p; p += (size_t)3 * D * D * 2;
    unsigned short* Wrh = (unsigned short*)p; p += (size_t)3 * D * D * 2;
    unsigned short* Wrl = (unsigned short*)p; p += (size_t)3 * D * D * 2;
    unsigned short* pWh = (unsigned short*)p; p += (size_t)D * D * 2;
    unsigned short* pWl = (unsigned short*)p; p += (size_t)D * D * 2;
    int* deg     = (int*)p; p += (size_t)N_NODES * 4;
    float* invd  = (float*)p; p += (size_t)N_NODES * 4;
    int* offs    = (int*)p; p += (size_t)(N_NODES + 2) * 4;
    int* cursor  = (int*)p; p += (size_t)N_NODES * 4;
    int* csr_src = (int*)p; p += (size_t)N_EDGES * 4;
    int* bsums   = (int*)p; p += 512 * 4;
    int* bcur    = (int*)p; p += 512 * 4;

    // aliases: xf16 lives in h1 (dead until layer-1 writes); pairs live in h0 (dead until layer-0 writes)
    unsigned short* xf = (unsigned short*)h1;
    uint2* pairs = (uint2*)h0;

    const int* src = ei;
    const int* dst = ei + N_EDGES;

    // weight splits (RNE) + x fp16 copy
    k_cvt_split<<<(3 * D * D / 4 + 255) / 256, 256, 0, stream>>>(WlAll, Wlh, Wll, 3 * D * D / 4);
    k_cvt_split<<<(3 * D * D / 4 + 255) / 256, 256, 0, stream>>>(WrAll, Wrh, Wrl, 3 * D * D / 4);
    k_cvt_split<<<(D * D / 4 + 255) / 256, 256, 0, stream>>>(projW, pWh, pWl, D * D / 4);
    k_cvt_f16<<<(N_NODES * D / 4 + 255) / 256, 256, 0, stream>>>(x, xf, N_NODES * D / 4);

    // CSR build: hist -> scan -> bucket scatter -> local fill
    hipMemsetAsync(deg, 0, (size_t)N_NODES * 4, stream);
    k_hist<<<(N_EDGES + 255) / 256, 256, 0, stream>>>(dst, deg);
    int nb = (N_NODES + 255) / 256;
    k_scan1<<<nb, 256, 0, stream>>>(deg, offs, bsums);
    k_scan2<<<1, 512, 0, stream>>>(bsums, nb);
    k_scan3<<<nb, 256, 0, stream>>>(deg, offs, bsums, cursor, invd);
    k_binit<<<2, 256, 0, stream>>>(offs, bcur);
    k_bucket<<<NBKT, 256, 0, stream>>>(src, dst, bcur, pairs);
    k_fill2<<<NBKT, 256, 0, stream>>>(pairs, offs, cursor, csr_src);

    int gl = (N_NODES + 127) / 128;   // 782

    // layer 0: h = x; skip = x@projW^T+projB fused; writes h0 + h0f
    k_agg_f16<<<N_NODES / 4, 256, 0, stream>>>(xf, offs, csr_src, invd, agg);
    k_layer<0><<<gl, 256, 0, stream>>>(agg, x, nullptr,
                                       Wlh, Wll, Wrh, Wrl, pWh, pWl, projB,
                                       lbAll, gAll, btAll, h0, h0f,
                                       nullptr, nullptr, nullptr, nullptr, nullptr);
    // layer 1: h = h0, skip = h0; writes h1 + h1f
    k_agg_f16<<<N_NODES / 4, 256, 0, stream>>>(h0f, offs, csr_src, invd, agg);
    k_layer<1><<<gl, 256, 0, stream>>>(agg, h0, h0,
                                       Wlh + D * D, Wll + D * D, Wrh + D * D, Wrl + D * D,
                                       nullptr, nullptr, nullptr,
                                       lbAll + D, gAll + D, btAll + D, h1, h1f,
                                       nullptr, nullptr, nullptr, nullptr, nullptr);
    // layer 2: h = h1, skip = h1; fused head -> out
    k_agg_f16<<<N_NODES / 4, 256, 0, stream>>>(h1f, offs, csr_src, invd, agg);
    k_layer<2><<<gl, 256, 0, stream>>>(agg, h1, h1,
                                       Wlh + 2 * D * D, Wll + 2 * D * D,
                                       Wrh + 2 * D * D, Wrl + 2 * D * D,
                                       nullptr, nullptr, nullptr,
                                       lbAll + 2 * D, gAll + 2 * D, btAll + 2 * D,
                                       nullptr, nullptr,
                                       hw, hbias, rr, alpha, out);
}

// Round 12
// 634.854 us; speedup vs baseline: 3.3355x; 1.0743x over previous
//
#include <hip/hip_runtime.h>
#include <math.h>

#define N_NODES 100000
#define N_EDGES 1600000
#define D 128
#define NBKT 391   // ceil(N_NODES/256) buckets of 256 dst nodes

typedef __attribute__((ext_vector_type(8))) short short8;
typedef __attribute__((ext_vector_type(4))) float floatx4;

__device__ __forceinline__ float bf2f(unsigned short u) {
    union { unsigned int i; float f; } v;
    v.i = ((unsigned int)u) << 16;
    return v.f;
}
__device__ __forceinline__ unsigned short f2bf(float f) {
    union { float f; unsigned int i; } v;
    v.f = f;
    unsigned int u = v.i;
    u += 0x7fffu + ((u >> 16) & 1u);
    return (unsigned short)(u >> 16);
}
__device__ __forceinline__ unsigned short f2h(float f) {
    union { _Float16 h; unsigned short u; } c;
    c.h = (_Float16)f;
    return c.u;
}
__device__ __forceinline__ float h2f(unsigned short u) {
    union { unsigned short u; _Float16 h; } c;
    c.u = u;
    return (float)c.h;
}

// split 8 consecutive fp32 into hi/lo bf16 fragments (RNE) — in-register, R3/R8-proven
__device__ __forceinline__ void split8(const float* __restrict__ p, short8& hi, short8& lo) {
    float4 v0 = *(const float4*)p;
    float4 v1 = *(const float4*)(p + 4);
    float f[8] = {v0.x, v0.y, v0.z, v0.w, v1.x, v1.y, v1.z, v1.w};
#pragma unroll
    for (int i = 0; i < 8; ++i) {
        unsigned short h = f2bf(f[i]);
        hi[i] = (short)h;
        lo[i] = (short)f2bf(f[i] - bf2f(h));
    }
}

// stage ONE 32KB weight array into LDS, fragment-major:
// entry e = (ct*4+ks)*64 + lane  holds  W[ct*16+(lane&15)][ks*32+(lane>>4)*8 .. +8]
__device__ __forceinline__ void stage1(unsigned short* sW,
                                       const unsigned short* __restrict__ W, int tid) {
#pragma unroll
    for (int i = 0; i < 8; ++i) {
        int e = tid + 256 * i;
        int ct = e >> 8;
        int ks = (e >> 6) & 3;
        int q = (e >> 4) & 3;
        int l = e & 15;
        size_t g = (size_t)(ct * 16 + l) * D + ks * 32 + q * 8;
        *(uint4*)(sW + (size_t)e * 8) = *(const uint4*)(W + g);
    }
}

// ---------------- weights: fp32 -> (hi,lo) bf16 RNE split ----------------
__global__ void k_cvt_split(const float* __restrict__ s, unsigned short* __restrict__ hi,
                            unsigned short* __restrict__ lo, int n4) {
    int i = blockIdx.x * 256 + threadIdx.x;
    if (i < n4) {
        float4 v = ((const float4*)s)[i];
        float f[4] = {v.x, v.y, v.z, v.w};
        ushort4 h, l;
        unsigned short* hp = (unsigned short*)&h;
        unsigned short* lp = (unsigned short*)&l;
#pragma unroll
        for (int c = 0; c < 4; ++c) {
            unsigned short hh = f2bf(f[c]);
            hp[c] = hh;
            lp[c] = f2bf(f[c] - bf2f(hh));
        }
        ((ushort4*)hi)[i] = h;
        ((ushort4*)lo)[i] = l;
    }
}

// ---------------- x: fp32 -> fp16 (gather copy only) ----------------
__global__ void k_cvt_f16(const float* __restrict__ s, unsigned short* __restrict__ d, int n4) {
    int i = blockIdx.x * 256 + threadIdx.x;
    if (i < n4) {
        float4 v = ((const float4*)s)[i];
        ushort4 o;
        o.x = f2h(v.x); o.y = f2h(v.y); o.z = f2h(v.z); o.w = f2h(v.w);
        ((ushort4*)d)[i] = o;
    }
}

// ---------------- CSR build ----------------
__global__ void k_hist(const int* __restrict__ dst, int* __restrict__ deg) {
    int e = blockIdx.x * 256 + threadIdx.x;
    if (e < N_EDGES) atomicAdd(&deg[dst[e]], 1);
}

__global__ void k_scan1(const int* __restrict__ deg, int* __restrict__ offs,
                        int* __restrict__ bsums) {
    __shared__ int tmp[256];
    int tid = threadIdx.x;
    int i = blockIdx.x * 256 + tid;
    int v = (i < N_NODES) ? deg[i] : 0;
    tmp[tid] = v;
    __syncthreads();
    for (int off = 1; off < 256; off <<= 1) {
        int t = (tid >= off) ? tmp[tid - off] : 0;
        __syncthreads();
        if (tid >= off) tmp[tid] += t;
        __syncthreads();
    }
    if (i < N_NODES) offs[i] = tmp[tid] - v;
    if (tid == 255) bsums[blockIdx.x] = tmp[255];
}

__global__ void k_scan2(int* __restrict__ bsums, int nb) {
    __shared__ int tmp[512];
    int tid = threadIdx.x;
    int v = (tid < nb) ? bsums[tid] : 0;
    tmp[tid] = v;
    __syncthreads();
    for (int off = 1; off < 512; off <<= 1) {
        int t = (tid >= off) ? tmp[tid - off] : 0;
        __syncthreads();
        if (tid >= off) tmp[tid] += t;
        __syncthreads();
    }
    if (tid < nb) bsums[tid] = tmp[tid] - v;
}

__global__ void k_scan3(const int* __restrict__ deg, int* __restrict__ offs,
                        const int* __restrict__ bsums, int* __restrict__ cursor,
                        float* __restrict__ inv_deg) {
    int i = blockIdx.x * 256 + threadIdx.x;
    if (i < N_NODES) {
        int o = offs[i] + bsums[blockIdx.x];
        offs[i] = o;
        cursor[i] = o;
        int d = deg[i];
        inv_deg[i] = 1.0f / (float)(d > 1 ? d : 1);
        if (i == 0) offs[N_NODES] = N_EDGES;
    }
}

__global__ void k_binit(const int* __restrict__ offs, int* __restrict__ bcur) {
    int b = blockIdx.x * 256 + threadIdx.x;
    if (b < NBKT) bcur[b] = offs[b << 8];
}

// pass A: scatter (src,dst) pairs bucket-contiguous (dst>>8 buckets)
__global__ __launch_bounds__(256) void k_bucket(const int* __restrict__ src,
                                                const int* __restrict__ dst,
                                                int* __restrict__ bcur, uint2* __restrict__ pairs) {
    __shared__ int cnt[NBKT];
    __shared__ int off[NBKT];
    int tid = threadIdx.x;
    for (int i = tid; i < NBKT; i += 256) cnt[i] = 0;
    __syncthreads();
    int e0 = blockIdx.x * 4096;
    int mydst[16], mysrc[16];
#pragma unroll
    for (int i = 0; i < 16; ++i) {
        int e = e0 + tid + i * 256;
        int d = (e < N_EDGES) ? dst[e] : -1;
        mydst[i] = d;
        mysrc[i] = (e < N_EDGES) ? src[e] : 0;
        if (d >= 0) atomicAdd(&cnt[d >> 8], 1);
    }
    __syncthreads();
    for (int b = tid; b < NBKT; b += 256) {
        int c = cnt[b];
        off[b] = c ? atomicAdd(&bcur[b], c) : 0;
    }
    __syncthreads();
#pragma unroll
    for (int i = 0; i < 16; ++i) {
        int d = mydst[i];
        if (d >= 0) {
            int p = atomicAdd(&off[d >> 8], 1);
            pairs[p] = make_uint2((unsigned)mysrc[i], (unsigned)d);
        }
    }
}

// pass B: one block per bucket — csr writes confined to one ~16KB region per block
__global__ __launch_bounds__(256) void k_fill2(const uint2* __restrict__ pairs,
                                               const int* __restrict__ offs,
                                               int* __restrict__ cursor, int* __restrict__ csr_src) {
    int b = blockIdx.x;
    int beg = offs[b << 8];
    int endn = (b + 1) << 8;
    if (endn > N_NODES) endn = N_NODES;
    int end = offs[endn];
    for (int e = beg + threadIdx.x; e < end; e += 256) {
        uint2 pr = pairs[e];
        int p = atomicAdd(&cursor[pr.y], 1);
        csr_src[p] = (int)pr.x;
    }
}

// ---------------- mean aggregation: dual-node waves, fp16 gather -> fp32 agg --------
// half-wave (32 lanes) per node; lane reads uint2 = 4 fp16 cols
__global__ void k_agg_f16(const unsigned short* __restrict__ hf, const int* __restrict__ offs,
                          const int* __restrict__ csr_src, const float* __restrict__ inv_deg,
                          float* __restrict__ agg) {
    int gw = (blockIdx.x * 256 + threadIdx.x) >> 6;   // global wave id
    int lane = threadIdx.x & 63;
    int half = lane >> 5, l32 = lane & 31;
    int node = gw * 2 + half;
    int beg = offs[node], end = offs[node + 1];
    float a0 = 0.f, a1 = 0.f, a2 = 0.f, a3 = 0.f;
    int e = beg;
    for (; e + 7 < end; e += 8) {
        int ss[8];
#pragma unroll
        for (int i = 0; i < 8; ++i) ss[i] = csr_src[e + i];
        uint2 vv[8];
#pragma unroll
        for (int i = 0; i < 8; ++i)
            vv[i] = ((const uint2*)(hf + (size_t)ss[i] * D))[l32];
#pragma unroll
        for (int i = 0; i < 8; ++i) {
            a0 += h2f((unsigned short)(vv[i].x & 0xffffu));
            a1 += h2f((unsigned short)(vv[i].x >> 16));
            a2 += h2f((unsigned short)(vv[i].y & 0xffffu));
            a3 += h2f((unsigned short)(vv[i].y >> 16));
        }
    }
    for (; e + 3 < end; e += 4) {
        int ss[4];
#pragma unroll
        for (int i = 0; i < 4; ++i) ss[i] = csr_src[e + i];
        uint2 vv[4];
#pragma unroll
        for (int i = 0; i < 4; ++i)
            vv[i] = ((const uint2*)(hf + (size_t)ss[i] * D))[l32];
#pragma unroll
        for (int i = 0; i < 4; ++i) {
            a0 += h2f((unsigned short)(vv[i].x & 0xffffu));
            a1 += h2f((unsigned short)(vv[i].x >> 16));
            a2 += h2f((unsigned short)(vv[i].y & 0xffffu));
            a3 += h2f((unsigned short)(vv[i].y >> 16));
        }
    }
    for (; e < end; ++e) {
        int s = csr_src[e];
        uint2 v = ((const uint2*)(hf + (size_t)s * D))[l32];
        a0 += h2f((unsigned short)(v.x & 0xffffu));
        a1 += h2f((unsigned short)(v.x >> 16));
        a2 += h2f((unsigned short)(v.y & 0xffffu));
        a3 += h2f((unsigned short)(v.y >> 16));
    }
    float id = inv_deg[node];
    float4 o;
    o.x = a0 * id; o.y = a1 * id; o.z = a2 * id; o.w = a3 * id;
    ((float4*)(agg + (size_t)node * D))[l32] = o;
}

// ---------------- fused SAGE layer: 64-row blocks, 32KB LDS, hi/lo phases ----------------
// MODE 0: + fused residual projection (skip = x@projW^T+projB), writes hout + houtf16
// MODE 1: skip = skipf (fp32), writes hout + houtf16
// MODE 2: skip = skipf; fused head -> outp; no h writes
template <int MODE>
__global__ __launch_bounds__(256, 3) void k_layer(
    const float* __restrict__ aggf, const float* __restrict__ hinf,
    const float* __restrict__ skipf,
    const unsigned short* __restrict__ Wlh, const unsigned short* __restrict__ Wll,
    const unsigned short* __restrict__ Wrh, const unsigned short* __restrict__ Wrl,
    const unsigned short* __restrict__ pWh, const unsigned short* __restrict__ pWl,
    const float* __restrict__ projB,
    const float* __restrict__ lb, const float* __restrict__ g,
    const float* __restrict__ beta,
    float* __restrict__ hout, unsigned short* __restrict__ houtf,
    const float* __restrict__ hw, const float* __restrict__ hb_bias,
    const float* __restrict__ rr, const float* __restrict__ alphap,
    float* __restrict__ outp) {
    __shared__ unsigned short sW[16384];   // 32KB, one weight array at a time

    int tid = threadIdx.x;
    int w = tid >> 6, lane = tid & 63;
    int quad = lane >> 4, l16 = lane & 15;
    int base = blockIdx.x * 64 + w * 16;

    int ar = base + l16; if (ar > N_NODES - 1) ar = N_NODES - 1;
    const float* aggr = aggf + (size_t)ar * D;
    const float* hinr = hinf + (size_t)ar * D;
    int koff = quad * 8;

    floatx4 z = {0.f, 0.f, 0.f, 0.f};
    floatx4 acc[8];
#pragma unroll
    for (int ct = 0; ct < 8; ++ct) acc[ct] = z;

    // A-splits for agg (reused across Wl hi and lo phases)
    short8 ah[4], al[4];
#pragma unroll
    for (int ks = 0; ks < 4; ++ks) split8(aggr + ks * 32 + koff, ah[ks], al[ks]);

    // phase 1: Wl hi  -> A_hi*W_hi + A_lo*W_hi
    stage1(sW, Wlh, tid);
    __syncthreads();
#pragma unroll
    for (int ks = 0; ks < 4; ++ks)
#pragma unroll
        for (int ct = 0; ct < 8; ++ct) {
            short8 wf = *(const short8*)(sW + ((ct * 4 + ks) * 64 + lane) * 8);
            acc[ct] = __builtin_amdgcn_mfma_f32_16x16x32_bf16(ah[ks], wf, acc[ct], 0, 0, 0);
            acc[ct] = __builtin_amdgcn_mfma_f32_16x16x32_bf16(al[ks], wf, acc[ct], 0, 0, 0);
        }
    __syncthreads();
    // phase 2: Wl lo  -> A_hi*W_lo
    stage1(sW, Wll, tid);
    __syncthreads();
#pragma unroll
    for (int ks = 0; ks < 4; ++ks)
#pragma unroll
        for (int ct = 0; ct < 8; ++ct) {
            short8 wf = *(const short8*)(sW + ((ct * 4 + ks) * 64 + lane) * 8);
            acc[ct] = __builtin_amdgcn_mfma_f32_16x16x32_bf16(ah[ks], wf, acc[ct], 0, 0, 0);
        }
    __syncthreads();

    // A-splits for hin (reused for Wr and, MODE 0, projW phases)
    short8 bh[4], blo[4];
#pragma unroll
    for (int ks = 0; ks < 4; ++ks) split8(hinr + ks * 32 + koff, bh[ks], blo[ks]);

    // phase 3: Wr hi
    stage1(sW, Wrh, tid);
    __syncthreads();
#pragma unroll
    for (int ks = 0; ks < 4; ++ks)
#pragma unroll
        for (int ct = 0; ct < 8; ++ct) {
            short8 wf = *(const short8*)(sW + ((ct * 4 + ks) * 64 + lane) * 8);
            acc[ct] = __builtin_amdgcn_mfma_f32_16x16x32_bf16(bh[ks], wf, acc[ct], 0, 0, 0);
            acc[ct] = __builtin_amdgcn_mfma_f32_16x16x32_bf16(blo[ks], wf, acc[ct], 0, 0, 0);
        }
    __syncthreads();
    // phase 4: Wr lo
    stage1(sW, Wrl, tid);
    __syncthreads();
#pragma unroll
    for (int ks = 0; ks < 4; ++ks)
#pragma unroll
        for (int ct = 0; ct < 8; ++ct) {
            short8 wf = *(const short8*)(sW + ((ct * 4 + ks) * 64 + lane) * 8);
            acc[ct] = __builtin_amdgcn_mfma_f32_16x16x32_bf16(bh[ks], wf, acc[ct], 0, 0, 0);
        }

    floatx4 accR[8];
    if (MODE == 0) {
#pragma unroll
        for (int ct = 0; ct < 8; ++ct) accR[ct] = z;
        __syncthreads();
        stage1(sW, pWh, tid);
        __syncthreads();
#pragma unroll
        for (int ks = 0; ks < 4; ++ks)
#pragma unroll
            for (int ct = 0; ct < 8; ++ct) {
                short8 wf = *(const short8*)(sW + ((ct * 4 + ks) * 64 + lane) * 8);
                accR[ct] = __builtin_amdgcn_mfma_f32_16x16x32_bf16(bh[ks], wf, accR[ct], 0, 0, 0);
                accR[ct] = __builtin_amdgcn_mfma_f32_16x16x32_bf16(blo[ks], wf, accR[ct], 0, 0, 0);
            }
        __syncthreads();
        stage1(sW, pWl, tid);
        __syncthreads();
#pragma unroll
        for (int ks = 0; ks < 4; ++ks)
#pragma unroll
            for (int ct = 0; ct < 8; ++ct) {
                short8 wf = *(const short8*)(sW + ((ct * 4 + ks) * 64 + lane) * 8);
                accR[ct] = __builtin_amdgcn_mfma_f32_16x16x32_bf16(bh[ks], wf, accR[ct], 0, 0, 0);
            }
    }

    // bias + relu in-register
    float lbv[8], gv[8], bv[8];
#pragma unroll
    for (int ct = 0; ct < 8; ++ct) {
        int n = ct * 16 + l16;
        lbv[ct] = lb[n];
        gv[ct] = g[n];
        bv[ct] = beta[n];
    }
#pragma unroll
    for (int ct = 0; ct < 8; ++ct)
#pragma unroll
        for (int r = 0; r < 4; ++r)
            acc[ct][r] = fmaxf(acc[ct][r] + lbv[ct], 0.f);

    // LN stats per row (row = quad*4+r), in-register
    float mu[4], rs[4];
#pragma unroll
    for (int r = 0; r < 4; ++r) {
        float s = 0.f, ss = 0.f;
#pragma unroll
        for (int ct = 0; ct < 8; ++ct) {
            float v = acc[ct][r];
            s += v;
            ss += v * v;
        }
#pragma unroll
        for (int m = 1; m < 16; m <<= 1) {
            s += __shfl_xor(s, m, 64);
            ss += __shfl_xor(ss, m, 64);
        }
        float m_ = s * (1.0f / 128.0f);
        float v_ = ss * (1.0f / 128.0f) - m_ * m_;
        mu[r] = m_;
        rs[r] = rsqrtf(v_ + 1e-5f);
    }

    float pbv[8], hwv[8];
    if (MODE == 0) {
#pragma unroll
        for (int ct = 0; ct < 8; ++ct) pbv[ct] = projB[ct * 16 + l16];
    }
    if (MODE == 2) {
#pragma unroll
        for (int ct = 0; ct < 8; ++ct) hwv[ct] = hw[ct * 16 + l16];
    }

    // epilogue
#pragma unroll
    for (int r = 0; r < 4; ++r) {
        int crow = base + quad * 4 + r;
        bool valid = (crow < N_NODES);
        float m_ = mu[r], rs_ = rs[r];
        size_t ro = (size_t)crow * D;
        if (MODE == 2) {
            float s = 0.f;
#pragma unroll
            for (int ct = 0; ct < 8; ++ct) {
                int col = ct * 16 + l16;
                float sk = valid ? skipf[ro + col] : 0.f;
                float o = (acc[ct][r] - m_) * rs_ * gv[ct] + bv[ct] + sk;
                s += o * hwv[ct];
            }
#pragma unroll
            for (int m = 1; m < 16; m <<= 1) s += __shfl_xor(s, m, 64);
            if (l16 == 0 && valid) {
                float a = 1.0f / (1.0f + expf(-alphap[0]));
                outp[crow] = a * rr[crow] + (1.0f - a) * (s + hb_bias[0]);
            }
        } else {
            if (!valid) continue;
#pragma unroll
            for (int ct = 0; ct < 8; ++ct) {
                int col = ct * 16 + l16;
                float sk = (MODE == 0) ? (accR[ct][r] + pbv[ct]) : skipf[ro + col];
                float o = (acc[ct][r] - m_) * rs_ * gv[ct] + bv[ct] + sk;
                hout[ro + col] = o;
                houtf[ro + col] = f2h(o);
            }
        }
    }
}

// ---------------- launch ----------------
extern "C" void kernel_launch(void* const* d_in, const int* in_sizes, int n_in,
                              void* d_out, int out_size, void* d_ws, size_t ws_size,
                              hipStream_t stream) {
    const float* x     = (const float*)d_in[0];
    const int*   ei    = (const int*)d_in[1];
    const float* rr    = (const float*)d_in[2];
    const float* projW = (const float*)d_in[3];
    const float* projB = (const float*)d_in[4];
    const float* WlAll = (const float*)d_in[5];
    const float* lbAll = (const float*)d_in[6];
    const float* WrAll = (const float*)d_in[7];
    const float* gAll  = (const float*)d_in[8];
    const float* btAll = (const float*)d_in[9];
    const float* hw    = (const float*)d_in[10];
    const float* hbias = (const float*)d_in[11];
    const float* alpha = (const float*)d_in[12];
    float* out = (float*)d_out;

    char* p = (char*)d_ws;
    float* agg = (float*)p; p += (size_t)N_NODES * D * 4;
    float* h0  = (float*)p; p += (size_t)N_NODES * D * 4;
    float* h1  = (float*)p; p += (size_t)N_NODES * D * 4;
    unsigned short* h0f = (unsigned short*)p; p += (size_t)N_NODES * D * 2;
    unsigned short* h1f = (unsigned short*)p; p += (size_t)N_NODES * D * 2;
    unsigned short* Wlh = (unsigned short*)p; p += (size_t)3 * D * D * 2;
    unsigned short* Wll = (unsigned short*)p; p += (size_t)3 * D * D * 2;
    unsigned short* Wrh = (unsigned short*)p; p += (size_t)3 * D * D * 2;
    unsigned short* Wrl = (unsigned short*)p; p += (size_t)3 * D * D * 2;
    unsigned short* pWh = (unsigned short*)p; p += (size_t)D * D * 2;
    unsigned short* pWl = (unsigned short*)p; p += (size_t)D * D * 2;
    int* deg     = (int*)p; p += (size_t)N_NODES * 4;
    float* invd  = (float*)p; p += (size_t)N_NODES * 4;
    int* offs    = (int*)p; p += (size_t)(N_NODES + 2) * 4;
    int* cursor  = (int*)p; p += (size_t)N_NODES * 4;
    int* csr_src = (int*)p; p += (size_t)N_EDGES * 4;
    int* bsums   = (int*)p; p += 512 * 4;
    int* bcur    = (int*)p; p += 512 * 4;

    // aliases: xf16 lives in h1 (dead until layer-1 writes); pairs live in h0 (dead until layer-0 writes)
    unsigned short* xf = (unsigned short*)h1;
    uint2* pairs = (uint2*)h0;

    const int* src = ei;
    const int* dst = ei + N_EDGES;

    // weight splits (RNE) + x fp16 copy
    k_cvt_split<<<(3 * D * D / 4 + 255) / 256, 256, 0, stream>>>(WlAll, Wlh, Wll, 3 * D * D / 4);
    k_cvt_split<<<(3 * D * D / 4 + 255) / 256, 256, 0, stream>>>(WrAll, Wrh, Wrl, 3 * D * D / 4);
    k_cvt_split<<<(D * D / 4 + 255) / 256, 256, 0, stream>>>(projW, pWh, pWl, D * D / 4);
    k_cvt_f16<<<(N_NODES * D / 4 + 255) / 256, 256, 0, stream>>>(x, xf, N_NODES * D / 4);

    // CSR build: hist -> scan -> bucket scatter -> local fill
    hipMemsetAsync(deg, 0, (size_t)N_NODES * 4, stream);
    k_hist<<<(N_EDGES + 255) / 256, 256, 0, stream>>>(dst, deg);
    int nb = (N_NODES + 255) / 256;
    k_scan1<<<nb, 256, 0, stream>>>(deg, offs, bsums);
    k_scan2<<<1, 512, 0, stream>>>(bsums, nb);
    k_scan3<<<nb, 256, 0, stream>>>(deg, offs, bsums, cursor, invd);
    k_binit<<<2, 256, 0, stream>>>(offs, bcur);
    k_bucket<<<NBKT, 256, 0, stream>>>(src, dst, bcur, pairs);
    k_fill2<<<NBKT, 256, 0, stream>>>(pairs, offs, cursor, csr_src);

    int gl = (N_NODES + 63) / 64;        // 1563
    int ga = N_NODES / 2 / 4;            // 12500 blocks (2 nodes per wave, 4 waves/block)

    // layer 0: h = x; skip = x@projW^T+projB fused; writes h0 + h0f
    k_agg_f16<<<ga, 256, 0, stream>>>(xf, offs, csr_src, invd, agg);
    k_layer<0><<<gl, 256, 0, stream>>>(agg, x, nullptr,
                                       Wlh, Wll, Wrh, Wrl, pWh, pWl, projB,
                                       lbAll, gAll, btAll, h0, h0f,
                                       nullptr, nullptr, nullptr, nullptr, nullptr);
    // layer 1: h = h0, skip = h0; writes h1 + h1f
    k_agg_f16<<<ga, 256, 0, stream>>>(h0f, offs, csr_src, invd, agg);
    k_layer<1><<<gl, 256, 0, stream>>>(agg, h0, h0,
                                       Wlh + D * D, Wll + D * D, Wrh + D * D, Wrl + D * D,
                                       nullptr, nullptr, nullptr,
                                       lbAll + D, gAll + D, btAll + D, h1, h1f,
                                       nullptr, nullptr, nullptr, nullptr, nullptr);
    // layer 2: h = h1, skip = h1; fused head -> out
    k_agg_f16<<<ga, 256, 0, stream>>>(h1f, offs, csr_src, invd, agg);
    k_layer<2><<<gl, 256, 0, stream>>>(agg, h1, h1,
                                       Wlh + 2 * D * D, Wll + 2 * D * D,
                                       Wrh + 2 * D * D, Wrl + 2 * D * D,
                                       nullptr, nullptr, nullptr,
                                       lbAll + 2 * D, gAll + 2 * D, btAll + 2 * D,
                                       nullptr, nullptr,
                                       hw, hbias, rr, alpha, out);
}